// Round 12
// baseline (357.861 us; speedup 1.0000x reference)
//
#include <hip/hip_runtime.h>
#include <hip/hip_bf16.h>
#include <stdint.h>

// Problem constants (T5 encoder-decoder block)
#define T5_B   2
#define T5_T   2048
#define T5_S   2048
#define T5_D   768
#define T5_H   12
#define T5_HD  64
#define T5_DFF 3072
#define T5_NB  32
#define NROW   4096   // B*T

#define LOG2E 1.4426950408889634f

typedef __attribute__((ext_vector_type(8))) short bf16x8;
typedef __attribute__((ext_vector_type(4))) short short4v;
typedef __attribute__((ext_vector_type(4))) float f32x4;
typedef __attribute__((ext_vector_type(16))) float f32x16;

__device__ __forceinline__ unsigned short f2bf(float x) {
  unsigned int u = __float_as_uint(x);
  unsigned int r = (u + 0x7FFFu + ((u >> 16) & 1u)) >> 16;   // RNE
  return (unsigned short)r;
}

// 2^x via the native v_exp_f32 (gfx950 v_exp_f32 IS exp2)
__device__ __forceinline__ float fexp2(float x) {
  float d;
  asm("v_exp_f32 %0, %1" : "=v"(d) : "v"(x));
  return d;
}

__device__ __forceinline__ void load_lds16(const void* g, void* l) {
  __builtin_amdgcn_global_load_lds(
      (__attribute__((address_space(1))) void*)(const_cast<void*>(g)),
      (__attribute__((address_space(3))) void*)(l), 16, 0, 0);
}

__device__ __forceinline__ unsigned cvt_pk_bf16(float lo_, float hi_) {
  unsigned d;
  asm("v_cvt_pk_bf16_f32 %0, %1, %2" : "=v"(d) : "v"(lo_), "v"(hi_));
  return d;
}

__device__ __forceinline__ f32x4 mfma16(short4v a, short4v b, f32x4 c) {
#if __has_builtin(__builtin_amdgcn_mfma_f32_16x16x16bf16_1k)
  return __builtin_amdgcn_mfma_f32_16x16x16bf16_1k(a, b, c, 0, 0, 0);
#else
  asm volatile("v_mfma_f32_16x16x16_bf16 %0, %1, %2, %0" : "+v"(c) : "v"(a), "v"(b));
  return c;
#endif
}

// bijective XCD chunk swizzle (m204): 8 XCDs, contiguous chunk per XCD
__device__ __forceinline__ int xcd_swz(int f, int nwg) {
  int q8 = nwg >> 3, r8 = nwg & 7, xcd = f & 7, base = f >> 3;
  return (xcd < r8 ? xcd * (q8 + 1) : r8 * (q8 + 1) + (xcd - r8) * q8) + base;
}

// ---------------------------------------------------------------------------
// GEMM body: C[M][N] = A[M][K](bf16) * Bt[N][K](bf16)^T.
// TM x TN tile, BK=64, XOR-swizzled LDS rows, 4 waves.
// 128x128 tiles: 32x32x16 MFMA. 64x64 tiles: 16x16x32 MFMA.
// NBUF-buffered, (NBUF-1)-deep prefetch with counted vmcnt.
// EPI: 0 = bf16 store; 1 = f32 store acc+res; 2 = bf16 relu store;
//      3 = bf16 store w/ cols<qe scaled by LOG2E, cols>=vcol0 -> vT layout;
//      4 = bf16 store scaled by LOG2E.
// ---------------------------------------------------------------------------
template <int TM, int TN, int EPI, int NBUF>
__device__ __forceinline__ void gemm_body(
    int f, int gx, int nwg,
    const unsigned short* __restrict__ A, const unsigned short* __restrict__ Bt,
    void* __restrict__ C, const float* __restrict__ res, int N, int K,
    unsigned short* LDS, unsigned short* vtp = nullptr, int vcol0 = 0, int qe = 0) {
  constexpr bool USE32 = (TM >= 128 && TN >= 128);
  constexpr int WR = (TM >= 128) ? 2 : 1;
  constexpr int WC = 4 / WR;
  constexpr int AM = TM / WR / 16;
  constexpr int AN = TN / WC / 16;
  constexpr int CHA = TM / 8, CHB = TN / 8, CPW = (CHA + CHB) / 4;
  constexpr int BUFSH = (TM + TN) * 64;   // shorts per buffer
  constexpr int DEPTH = NBUF - 1;
  const int tid = threadIdx.x, lane = tid & 63, wv = tid >> 6;
  const int lo = lane & 15, hi = lane >> 4;
  const int l5 = lane >> 5, l31 = lane & 31;
  const int wr = wv / WC, wc = wv % WC;
  const int wg = xcd_swz(f, nwg);
  const int m0 = (wg / gx) * TM, n0 = (wg % gx) * TN;

  f32x4 acc[USE32 ? 1 : AM][USE32 ? 1 : AN];
  f32x16 acc32[USE32 ? 2 : 1][USE32 ? 2 : 1];
  if (USE32) {
#pragma unroll
    for (int i = 0; i < (USE32 ? 2 : 1); ++i)
#pragma unroll
      for (int j = 0; j < (USE32 ? 2 : 1); ++j)
#pragma unroll
        for (int r = 0; r < 16; ++r) acc32[i][j][r] = 0.f;
  } else {
#pragma unroll
    for (int i = 0; i < (USE32 ? 1 : AM); ++i)
#pragma unroll
      for (int j = 0; j < (USE32 ? 1 : AN); ++j) acc[i][j] = f32x4{0.f, 0.f, 0.f, 0.f};
  }

  const int srr  = lane >> 3;                    // row within 8-row chunk
  const int scol = ((lane & 7) ^ srr) * 8;       // pre-swizzled col (halfwords)

  auto stage = [&](int k0, int bsel) {
    unsigned short* Ab = LDS + bsel * BUFSH;
    unsigned short* Bb = Ab + TM * 64;
#pragma unroll
    for (int j = 0; j < CPW; ++j) {
      int c = wv * CPW + j;
      if (c < CHA)
        load_lds16(A + (size_t)(m0 + c * 8 + srr) * K + k0 + scol, Ab + c * 512);
      else {
        int c2 = c - CHA;
        load_lds16(Bt + (size_t)(n0 + c2 * 8 + srr) * K + k0 + scol, Bb + c2 * 512);
      }
    }
  };

  const int nIt = K >> 6;
#pragma unroll
  for (int p = 0; p < DEPTH; ++p)
    if (p < nIt) stage(p << 6, p % NBUF);

  for (int it = 0; it < nIt; ++it) {
    const int bsel = it % NBUF;
    if (it + DEPTH < nIt) {
      stage((it + DEPTH) << 6, (it + DEPTH) % NBUF);
      asm volatile("s_waitcnt vmcnt(%0)" :: "n"(DEPTH * CPW) : "memory");
    } else if (it + 1 < nIt) {
      asm volatile("s_waitcnt vmcnt(%0)" :: "n"(CPW) : "memory");
    } else {
      asm volatile("s_waitcnt vmcnt(0)" ::: "memory");
    }
    __builtin_amdgcn_s_barrier();
    __builtin_amdgcn_sched_barrier(0);
    const unsigned short* Ab = LDS + bsel * BUFSH;
    const unsigned short* Bb = Ab + TM * 64;
    if (USE32) {
      // 32x32x16: 4 sub-K of 16; A row = lane&31, k-half = lane>>5
#pragma unroll
      for (int kk = 0; kk < 4; ++kk) {
        bf16x8 af[2], bfr[2];
#pragma unroll
        for (int i = 0; i < 2; ++i) {
          int row = wr * 64 + i * 32 + l31;
          unsigned by = (unsigned)(row * 128) + ((unsigned)(((kk * 2 + l5) ^ (row & 7))) << 4);
          af[i] = *(const bf16x8*)((const char*)Ab + by);
        }
#pragma unroll
        for (int j = 0; j < 2; ++j) {
          int row = wc * 64 + j * 32 + l31;
          unsigned by = (unsigned)(row * 128) + ((unsigned)(((kk * 2 + l5) ^ (row & 7))) << 4);
          bfr[j] = *(const bf16x8*)((const char*)Bb + by);
        }
        __builtin_amdgcn_s_setprio(1);
#pragma unroll
        for (int i = 0; i < 2; ++i)
#pragma unroll
          for (int j = 0; j < 2; ++j)
            acc32[i][j] = __builtin_amdgcn_mfma_f32_32x32x16_bf16(af[i], bfr[j], acc32[i][j], 0, 0, 0);
        __builtin_amdgcn_s_setprio(0);
      }
    } else {
#pragma unroll
      for (int kk = 0; kk < 2; ++kk) {
        bf16x8 af[AM], bfr[AN];
#pragma unroll
        for (int i = 0; i < AM; ++i) {
          int row = wr * (AM * 16) + i * 16 + lo;
          unsigned by = (unsigned)(row * 128) + ((unsigned)(((kk * 4 + hi) ^ (row & 7))) << 4);
          af[i] = *(const bf16x8*)((const char*)Ab + by);
        }
#pragma unroll
        for (int j = 0; j < AN; ++j) {
          int row = wc * (AN * 16) + j * 16 + lo;
          unsigned by = (unsigned)(row * 128) + ((unsigned)(((kk * 4 + hi) ^ (row & 7))) << 4);
          bfr[j] = *(const bf16x8*)((const char*)Bb + by);
        }
        __builtin_amdgcn_s_setprio(1);
#pragma unroll
        for (int i = 0; i < AM; ++i)
#pragma unroll
          for (int j = 0; j < AN; ++j)
            acc[i][j] = __builtin_amdgcn_mfma_f32_16x16x32_bf16(af[i], bfr[j], acc[i][j], 0, 0, 0);
        __builtin_amdgcn_s_setprio(0);
      }
    }
    __builtin_amdgcn_sched_barrier(0);
    __builtin_amdgcn_s_barrier();
  }

  if (USE32) {
    // C/D 32x32: col = lane&31, row = (r&3) + 8*(r>>2) + 4*(lane>>5)
#pragma unroll
    for (int i = 0; i < 2; ++i)
#pragma unroll
      for (int j = 0; j < 2; ++j) {
        int colb = n0 + wc * 64 + j * 32 + l31;
#pragma unroll
        for (int g = 0; g < 4; ++g) {
          int rowb = m0 + wr * 64 + i * 32 + g * 8 + 4 * l5;
          if (EPI == 3 && colb >= vcol0) {
            int cc = colb - vcol0, hh = cc >> 6, dd = cc & 63;
            int bb = rowb >> 11, tt = rowb & 2047;
            unsigned long long pk = (unsigned long long)f2bf(acc32[i][j][g * 4 + 0])
                                  | ((unsigned long long)f2bf(acc32[i][j][g * 4 + 1]) << 16)
                                  | ((unsigned long long)f2bf(acc32[i][j][g * 4 + 2]) << 32)
                                  | ((unsigned long long)f2bf(acc32[i][j][g * 4 + 3]) << 48);
            *(unsigned long long*)(vtp + ((size_t)((bb * 12 + hh) * 64 + dd)) * 2048 + tt) = pk;
          } else {
#pragma unroll
            for (int rr = 0; rr < 4; ++rr) {
              float v = acc32[i][j][g * 4 + rr];
              size_t idx = (size_t)(rowb + rr) * N + colb;
              if (EPI == 3) {
                if (colb < qe) v *= LOG2E;
                ((unsigned short*)C)[idx] = f2bf(v);
              } else if (EPI == 0) {
                ((unsigned short*)C)[idx] = f2bf(v);
              } else if (EPI == 1) {
                ((float*)C)[idx] = v + res[idx];
              } else if (EPI == 2) {
                ((unsigned short*)C)[idx] = f2bf(fmaxf(v, 0.0f));
              } else {
                ((unsigned short*)C)[idx] = f2bf(v * LOG2E);
              }
            }
          }
        }
      }
  } else {
#pragma unroll
    for (int mi = 0; mi < (USE32 ? 1 : AM); ++mi)
#pragma unroll
      for (int ni = 0; ni < (USE32 ? 1 : AN); ++ni) {
        int row = m0 + wr * (AM * 16) + mi * 16 + hi * 4;
        int col = n0 + wc * (AN * 16) + ni * 16 + lo;
#pragma unroll
        for (int r = 0; r < 4; ++r) {
          float v = acc[mi][ni][r];
          size_t idx = (size_t)(row + r) * N + col;
          if (EPI == 0 || EPI == 3) {
            ((unsigned short*)C)[idx] = f2bf(v);
          } else if (EPI == 1) {
            ((float*)C)[idx] = v + res[idx];
          } else if (EPI == 2) {
            ((unsigned short*)C)[idx] = f2bf(fmaxf(v, 0.0f));
          } else {
            ((unsigned short*)C)[idx] = f2bf(v * LOG2E);
          }
        }
      }
  }
}

template <int TM, int TN, int EPI, int NBUF>
__global__ __launch_bounds__(256)
void gemm_bt(const unsigned short* __restrict__ A, const unsigned short* __restrict__ Bt,
             void* __restrict__ C, const float* __restrict__ res, int N, int K) {
  __shared__ __align__(16) unsigned short LDS[NBUF * (TM + TN) * 64];
  int f = blockIdx.y * gridDim.x + blockIdx.x;
  gemm_body<TM, TN, EPI, NBUF>(f, gridDim.x, gridDim.x * gridDim.y, A, Bt, C, res, N, K, LDS);
}

// ---------------------------------------------------------------------------
// Mega prep: 10 weight transposes, enc f32->bf16, rp->u8, rmsnorm1.
// ---------------------------------------------------------------------------
struct PrepArgs {
  const float* wsrc[10];
  unsigned short* wdst[10];
  const float* enc; unsigned short* encb;
  const int* rp; unsigned char* rp8;
  const float* x; const float* snw; unsigned short* normb;
};

__global__ __launch_bounds__(256)
void prep_kernel(PrepArgs a) {
  __shared__ __align__(16) float tile[32][33];
  const int bid = blockIdx.x, tid = threadIdx.x;
  if (bid < 9216) {
    int widx, rem, Kd, Nd;
    if (bid < 4608)      { widx = bid / 576; rem = bid % 576;  Kd = 768;  Nd = 768;  }
    else if (bid < 6912) { widx = 8;         rem = bid - 4608; Kd = 768;  Nd = 3072; }
    else                 { widx = 9;         rem = bid - 6912; Kd = 3072; Nd = 768;  }
    const float* W = a.wsrc[widx];
    unsigned short* Wt = a.wdst[widx];
    int nb = Nd / 32;
    int n0 = (rem % nb) * 32, k0 = (rem / nb) * 32;
    int tx = tid & 31, ty = tid >> 5;
#pragma unroll
    for (int i = 0; i < 32; i += 8)
      tile[ty + i][tx] = W[(size_t)(k0 + ty + i) * Nd + n0 + tx];
    __syncthreads();
#pragma unroll
    for (int i = 0; i < 32; i += 8)
      Wt[(size_t)(n0 + ty + i) * Kd + k0 + tx] = f2bf(tile[tx][ty + i]);
  } else if (bid < 12288) {
    int i = (bid - 9216) * 256 + tid;
    float4 v = ((const float4*)a.enc)[i];
    unsigned long long pk = (unsigned long long)f2bf(v.x)
                          | ((unsigned long long)f2bf(v.y) << 16)
                          | ((unsigned long long)f2bf(v.z) << 32)
                          | ((unsigned long long)f2bf(v.w) << 48);
    *(unsigned long long*)(a.encb + (size_t)i * 4) = pk;
  } else if (bid < 13312) {
    int idx = (bid - 12288) * 256 + tid;          // 16 bytes per thread, identity
    const int4* src = (const int4*)(a.rp + (size_t)idx * 16);
    int4 v0 = src[0], v1 = src[1], v2 = src[2], v3 = src[3];
    uint4 o;
    o.x = (v0.x & 31) | ((v0.y & 31) << 8) | ((v0.z & 31) << 16) | ((v0.w & 31) << 24);
    o.y = (v1.x & 31) | ((v1.y & 31) << 8) | ((v1.z & 31) << 16) | ((v1.w & 31) << 24);
    o.z = (v2.x & 31) | ((v2.y & 31) << 8) | ((v2.z & 31) << 16) | ((v2.w & 31) << 24);
    o.w = (v3.x & 31) | ((v3.y & 31) << 8) | ((v3.z & 31) << 16) | ((v3.w & 31) << 24);
    ((uint4*)a.rp8)[idx] = o;
  } else {
    int row = bid - 13312;
    const float* r = a.x + (size_t)row * 768;
    float x0 = r[tid], x1 = r[tid + 256], x2 = r[tid + 512];
    float s = x0 * x0 + x1 * x1 + x2 * x2;
#pragma unroll
    for (int off = 32; off > 0; off >>= 1) s += __shfl_xor(s, off);
    float* wsm = &tile[0][0];
    int lane = tid & 63, wvv = tid >> 6;
    if (lane == 0) wsm[wvv] = s;
    __syncthreads();
    float tot = wsm[0] + wsm[1] + wsm[2] + wsm[3];
    float rinv = rsqrtf(tot * (1.0f / 768.0f) + 1e-6f);
    unsigned short* o = a.normb + (size_t)row * 768;
    o[tid]       = f2bf(x0 * rinv * a.snw[tid]);
    o[tid + 256] = f2bf(x1 * rinv * a.snw[tid + 256]);
    o[tid + 512] = f2bf(x2 * rinv * a.snw[tid + 512]);
  }
}

// ---------------------------------------------------------------------------
// RMSNorm standalone (stages 2 & 3)
// ---------------------------------------------------------------------------
__global__ __launch_bounds__(256)
void rmsnorm_kernel(const float* __restrict__ in, const float* __restrict__ w,
                    unsigned short* __restrict__ out) {
  int row = blockIdx.x, tid = threadIdx.x;
  const float* r = in + (size_t)row * 768;
  float x0 = r[tid], x1 = r[tid + 256], x2 = r[tid + 512];
  float s = x0 * x0 + x1 * x1 + x2 * x2;
#pragma unroll
  for (int off = 32; off > 0; off >>= 1) s += __shfl_xor(s, off);
  __shared__ float ws_[4];
  int lane = tid & 63, wv = tid >> 6;
  if (lane == 0) ws_[wv] = s;
  __syncthreads();
  float tot = ws_[0] + ws_[1] + ws_[2] + ws_[3];
  float rinv = rsqrtf(tot * (1.0f / 768.0f) + 1e-6f);
  unsigned short* o = out + (size_t)row * 768;
  o[tid]       = f2bf(x0 * rinv * w[tid]);
  o[tid + 256] = f2bf(x1 * rinv * w[tid + 256]);
  o[tid + 512] = f2bf(x2 * rinv * w[tid + 512]);
}

// ---------------------------------------------------------------------------
// Stage-1 mega kernel: QKV GEMM [0,576) (Q cols pre-scaled by LOG2E, V->vT1) +
// crossKV GEMM [576,960) (V->vT2) + pos_bias/out2 [960,5056).
// ---------------------------------------------------------------------------
struct Stage1Args {
  const unsigned short *normb, *wqkvT, *encb, *wckvT;
  unsigned short *qkv, *ckv, *vT1, *vT2;
  const int* rp; const float* rel;
  float *out1, *out2;
};

__global__ __launch_bounds__(256)
void stage1_kernel(Stage1Args a) {
  __shared__ __align__(16) unsigned short LDS[32768];
  const int bid = blockIdx.x, tid = threadIdx.x;
  if (bid < 576) {
    gemm_body<128, 128, 3, 2>(bid, 18, 576, a.normb, a.wqkvT, a.qkv, nullptr, 2304, 768,
                              LDS, a.vT1, 1536, 768);
  } else if (bid < 960) {
    gemm_body<128, 128, 3, 2>(bid - 576, 12, 384, a.encb, a.wckvT, a.ckv, nullptr, 1536, 768,
                              LDS, a.vT2, 768, 0);
  } else {
    const int p = bid - 960;
    float* rl = (float*)LDS;
    for (int i = tid; i < 384; i += 256) rl[i] = a.rel[i];
    __syncthreads();
    int t = p >> 1;
    int s = (p & 1) * 1024 + tid * 4;
    int4 nb = *(const int4*)(a.rp + (size_t)t * 2048 + s);
#pragma unroll
    for (int h = 0; h < 12; ++h) {
      float4 v = make_float4(rl[nb.x * 12 + h], rl[nb.y * 12 + h],
                             rl[nb.z * 12 + h], rl[nb.w * 12 + h]);
      *(float4*)(a.out1 + ((size_t)h * 2048 + t) * 2048 + s) = v;
    }
    size_t zbase = ((size_t)p * 256 + tid) * 8;
    float4 z = make_float4(0.f, 0.f, 0.f, 0.f);
    *(float4*)(a.out2 + zbase)     = z;
    *(float4*)(a.out2 + zbase + 4) = z;
  }
}

// ---------------------------------------------------------------------------
// Attention q-tile compute (swapped operands; lane owns q = lane&15).
// FIXED-BASE softmax: p = exp2(s), no max subtraction.
// ---------------------------------------------------------------------------
template <bool SELF>
__device__ __forceinline__ void attn_qcomp(
    const bf16x8& qf0, const bf16x8& qf1, f32x4* Oc, float& l_,
    const unsigned* nb4, const float* rel_l, int qrow, bool edge, int s0,
    const unsigned short* Kb, const unsigned short* Vb, int lo, int hi) {
  f32x4 S[4];
  __builtin_amdgcn_s_setprio(1);
#pragma unroll
  for (int ct = 0; ct < 4; ++ct) {
    int krow = ct * 16 + lo;
    unsigned by0 = ((unsigned)(krow * 128 + hi * 16))      ^ ((unsigned)(krow & 7) << 4);
    unsigned by1 = ((unsigned)(krow * 128 + 64 + hi * 16)) ^ ((unsigned)(krow & 7) << 4);
    bf16x8 kf0 = *(const bf16x8*)((const char*)Kb + by0);
    bf16x8 kf1 = *(const bf16x8*)((const char*)Kb + by1);
    f32x4 sa = f32x4{0.f, 0.f, 0.f, 0.f};
    sa = __builtin_amdgcn_mfma_f32_16x16x32_bf16(kf0, qf0, sa, 0, 0, 0);
    sa = __builtin_amdgcn_mfma_f32_16x16x32_bf16(kf1, qf1, sa, 0, 0, 0);
    S[ct] = sa;
  }
  __builtin_amdgcn_s_setprio(0);

  if constexpr (SELF) {
#pragma unroll
    for (int ct = 0; ct < 4; ++ct) {
#pragma unroll
      for (int r = 0; r < 4; ++r) {
        int s = s0 + ct * 16 + hi * 4 + r;
        float sc = S[ct][r] + rel_l[(nb4[ct] >> (8 * r)) & 31u];
        if (edge && s > qrow) sc = -1e30f;
        S[ct][r] = sc;
      }
    }
  }

  float rs = 0.f;
#pragma unroll
  for (int ct = 0; ct < 4; ++ct)
#pragma unroll
    for (int r = 0; r < 4; ++r) { float e = fexp2(S[ct][r]); S[ct][r] = e; rs += e; }
  l_ += rs;

  short4v pf[4];
#pragma unroll
  for (int ct = 0; ct < 4; ++ct) {
    union { unsigned u[2]; short4v s; } cv;
    cv.u[0] = cvt_pk_bf16(S[ct][0], S[ct][1]);
    cv.u[1] = cvt_pk_bf16(S[ct][2], S[ct][3]);
    pf[ct] = cv.s;
  }

  __builtin_amdgcn_s_setprio(1);
#pragma unroll
  for (int dt = 0; dt < 4; ++dt) {
    int vrow = dt * 16 + lo;
#pragma unroll
    for (int ct = 0; ct < 4; ++ct) {
      unsigned vb = ((unsigned)(vrow * 128 + ct * 32 + hi * 8)) ^ ((unsigned)(vrow & 7) << 4);
      short4v vf = *(const short4v*)((const char*)Vb + vb);
      Oc[dt] = mfma16(vf, pf[ct], Oc[dt]);
    }
  }
  __builtin_amdgcn_s_setprio(0);
}

__device__ __forceinline__ void attn_store(f32x4* Oc, float l_, unsigned short* yr) {
  l_ += __shfl_xor(l_, 16);
  l_ += __shfl_xor(l_, 32);
  float inv = 1.0f / l_;
#pragma unroll
  for (int dt = 0; dt < 4; ++dt) {
    unsigned long long pk = (unsigned long long)f2bf(Oc[dt][0] * inv)
                          | ((unsigned long long)f2bf(Oc[dt][1] * inv) << 16)
                          | ((unsigned long long)f2bf(Oc[dt][2] * inv) << 32)
                          | ((unsigned long long)f2bf(Oc[dt][3] * inv) << 48);
    *(unsigned long long*)(yr + dt * 16) = pk;
  }
}

// ---------------------------------------------------------------------------
// Self-attention: PAIRED q-tiles (i, 31-i). Bias dwords PREFETCHED one tile
// ahead (issued with stage(kt+1); the next top-of-loop vmcnt(0) drains them
// for free -> no mid-qcomp L2 stall). grid (16,12,2). LDS 32KB.
// ---------------------------------------------------------------------------
__global__ __launch_bounds__(256)
void attn_self_kernel(const unsigned short* __restrict__ qp,   // qkv, stride 2304
                      const unsigned short* __restrict__ kp,   // qkv+768
                      const unsigned short* __restrict__ vT,
                      const unsigned char* __restrict__ rp8,
                      const float* __restrict__ rel_emb,
                      unsigned short* __restrict__ yp) {
  __shared__ __align__(16) unsigned short Kls[2][4096];
  __shared__ __align__(16) unsigned short Vls[2][4096];
  __shared__ float rel_l[32];

  const int tid = threadIdx.x, lane = tid & 63, wv = tid >> 6;
  const int lo = lane & 15, hi = lane >> 4;
  const int wg = xcd_swz(blockIdx.x + 16 * (blockIdx.y + 12 * blockIdx.z), 384);
  const int xq = wg & 15, h = (wg >> 4) % 12, b = (wg >> 4) / 12;
  const int qta = xq, qtb = 31 - xq;
  const int ntiles = qtb + 1;

  if (tid < 32) rel_l[tid] = rel_emb[tid * 12 + h] * LOG2E;

  const int qA = qta * 64 + wv * 16 + lo;
  const int qB = qtb * 64 + wv * 16 + lo;
  const unsigned short* qrA = qp + (size_t)(b * T5_T + qA) * 2304 + h * 64 + hi * 8;
  const unsigned short* qrB = qp + (size_t)(b * T5_T + qB) * 2304 + h * 64 + hi * 8;
  const bf16x8 qa0 = *(const bf16x8*)qrA;
  const bf16x8 qa1 = *(const bf16x8*)(qrA + 32);
  const bf16x8 qb0 = *(const bf16x8*)qrB;
  const bf16x8 qb1 = *(const bf16x8*)(qrB + 32);
  const unsigned char* rpqA = rp8 + (size_t)qA * 2048 + hi * 4;
  const unsigned char* rpqB = rp8 + (size_t)qB * 2048 + hi * 4;

  f32x4 OA[4], OB[4];
  float lA = 0.f, lB = 0.f;
#pragma unroll
  for (int i = 0; i < 4; ++i) { OA[i] = f32x4{0.f, 0.f, 0.f, 0.f}; OB[i] = f32x4{0.f, 0.f, 0.f, 0.f}; }

  const int krr = lane >> 3;
  const int kd0 = ((lane & 7) ^ krr) * 8;

  auto stage = [&](int kt, int bsel) {
    const int s0 = kt * 64;
#pragma unroll
    for (int j = 0; j < 2; ++j) {
      int c = wv * 2 + j;
      int rr = c * 8 + krr;
      load_lds16(kp + (size_t)(b * 2048 + s0 + rr) * 2304 + h * 64 + kd0, &Kls[bsel][c * 512]);
      load_lds16(vT + (size_t)((b * 12 + h) * 64 + rr) * 2048 + s0 + kd0,  &Vls[bsel][c * 512]);
    }
  };

  stage(0, 0);

  // bias prefetch registers: cur = tile kt, nxt = tile kt+1
  unsigned nbA[4], nbB[4], nbAn[4], nbBn[4];
#pragma unroll
  for (int ct = 0; ct < 4; ++ct) nbAn[ct] = *(const unsigned*)(rpqA + ct * 16);
#pragma unroll
  for (int ct = 0; ct < 4; ++ct) nbBn[ct] = *(const unsigned*)(rpqB + ct * 16);

  for (int kt = 0; kt < ntiles; ++kt) {
    const int bsel = kt & 1;
    const int s0 = kt * 64;
    asm volatile("s_waitcnt vmcnt(0)" ::: "memory");
    __syncthreads();
    // rotate prefetched bias into cur; issue next tile's bias + stage
#pragma unroll
    for (int ct = 0; ct < 4; ++ct) { nbA[ct] = nbAn[ct]; nbB[ct] = nbBn[ct]; }
    if (kt + 1 < ntiles) {
      const int s1 = s0 + 64;
#pragma unroll
      for (int ct = 0; ct < 4; ++ct) nbAn[ct] = *(const unsigned*)(rpqA + s1 + ct * 16);
#pragma unroll
      for (int ct = 0; ct < 4; ++ct) nbBn[ct] = *(const unsigned*)(rpqB + s1 + ct * 16);
      stage(kt + 1, bsel ^ 1);
    }

    const unsigned short* Kb = &Kls[bsel][0];
    const unsigned short* Vb = &Vls[bsel][0];

    if (kt <= qta)
      attn_qcomp<true>(qa0, qa1, OA, lA, nbA, rel_l, qA, kt == qta, s0, Kb, Vb, lo, hi);
    attn_qcomp<true>(qb0, qb1, OB, lB, nbB, rel_l, qB, kt == qtb, s0, Kb, Vb, lo, hi);
  }

#if !__has_builtin(__builtin_amdgcn_mfma_f32_16x16x16bf16_1k)
  asm volatile("s_nop 7\n\ts_nop 7" ::: );
#endif

  attn_store(OA, lA, yp + (size_t)(b * T5_T + qA) * 768 + h * 64 + hi * 4);
  attn_store(OB, lB, yp + (size_t)(b * T5_T + qB) * 768 + h * 64 + hi * 4);
}

// ---------------------------------------------------------------------------
// Cross-attention: PAIRED q-tiles (2i, 2i+1), no bias/mask. grid (16,12,2).
// K/V staged once per pair.
// ---------------------------------------------------------------------------
__global__ __launch_bounds__(256)
void attn_cross_kernel(const unsigned short* __restrict__ qp,   // cq, stride 768
                       const unsigned short* __restrict__ kp,   // ckv, stride 1536
                       const unsigned short* __restrict__ vT,
                       unsigned short* __restrict__ yp) {
  __shared__ __align__(16) unsigned short Kls[2][4096];
  __shared__ __align__(16) unsigned short Vls[2][4096];

  const int tid = threadIdx.x, lane = tid & 63, wv = tid >> 6;
  const int lo = lane & 15, hi = lane >> 4;
  const int wg = xcd_swz(blockIdx.x + 16 * (blockIdx.y + 12 * blockIdx.z), 384);
  const int xq = wg & 15, h = (wg >> 4) % 12, b = (wg >> 4) / 12;

  const int qA = (xq * 2) * 64 + wv * 16 + lo;
  const int qB = (xq * 2 + 1) * 64 + wv * 16 + lo;
  const unsigned short* qrA = qp + (size_t)(b * T5_T + qA) * 768 + h * 64 + hi * 8;
  const unsigned short* qrB = qp + (size_t)(b * T5_T + qB) * 768 + h * 64 + hi * 8;
  const bf16x8 qa0 = *(const bf16x8*)qrA;
  const bf16x8 qa1 = *(const bf16x8*)(qrA + 32);
  const bf16x8 qb0 = *(const bf16x8*)qrB;
  const bf16x8 qb1 = *(const bf16x8*)(qrB + 32);

  f32x4 OA[4], OB[4];
  float lA = 0.f, lB = 0.f;
#pragma unroll
  for (int i = 0; i < 4; ++i) { OA[i] = f32x4{0.f, 0.f, 0.f, 0.f}; OB[i] = f32x4{0.f, 0.f, 0.f, 0.f}; }

  const int krr = lane >> 3;
  const int kd0 = ((lane & 7) ^ krr) * 8;

  auto stage = [&](int kt, int bsel) {
    const int s0 = kt * 64;
#pragma unroll
    for (int j = 0; j < 2; ++j) {
      int c = wv * 2 + j;
      int rr = c * 8 + krr;
      load_lds16(kp + (size_t)(b * 2048 + s0 + rr) * 1536 + h * 64 + kd0, &Kls[bsel][c * 512]);
      load_lds16(vT + (size_t)((b * 12 + h) * 64 + rr) * 2048 + s0 + kd0, &Vls[bsel][c * 512]);
    }
  };

  stage(0, 0);

  for (int kt = 0; kt < 32; ++kt) {
    const int bsel = kt & 1;
    asm volatile("s_waitcnt vmcnt(0)" ::: "memory");
    __syncthreads();
    if (kt + 1 < 32) stage(kt + 1, bsel ^ 1);
    const unsigned short* Kb = &Kls[bsel][0];
    const unsigned short* Vb = &Vls[bsel][0];
    attn_qcomp<false>(qa0, qa1, OA, lA, nullptr, nullptr, 0, false, kt * 64, Kb, Vb, lo, hi);
    attn_qcomp<false>(qb0, qb1, OB, lB, nullptr, nullptr, 0, false, kt * 64, Kb, Vb, lo, hi);
  }

#if !__has_builtin(__builtin_amdgcn_mfma_f32_16x16x16bf16_1k)
  asm volatile("s_nop 7\n\ts_nop 7" ::: );
#endif

  attn_store(OA, lA, yp + (size_t)(b * T5_T + qA) * 768 + h * 64 + hi * 4);
  attn_store(OB, lB, yp + (size_t)(b * T5_T + qB) * 768 + h * 64 + hi * 4);
}

// ---------------------------------------------------------------------------
extern "C" void kernel_launch(void* const* d_in, const int* in_sizes, int n_in,
                              void* d_out, int out_size, void* d_ws, size_t ws_size,
                              hipStream_t stream) {
  (void)in_sizes; (void)n_in; (void)out_size; (void)ws_size;
  const float* x    = (const float*)d_in[0];
  const int*   rp   = (const int*)d_in[2];
  const float* enc  = (const float*)d_in[3];
  const float* sn_w = (const float*)d_in[5];
  const float* wq   = (const float*)d_in[6];
  const float* wk   = (const float*)d_in[7];
  const float* wvw  = (const float*)d_in[8];
  const float* wo   = (const float*)d_in[9];
  const float* rel  = (const float*)d_in[10];
  const float* cn_w = (const float*)d_in[11];
  const float* cwq  = (const float*)d_in[12];
  const float* cwk  = (const float*)d_in[13];
  const float* cwv  = (const float*)d_in[14];
  const float* cwo  = (const float*)d_in[15];
  const float* pn_w = (const float*)d_in[16];
  const float* wi   = (const float*)d_in[17];
  const float* wo2  = (const float*)d_in[18];

  float* out0 = (float*)d_out;
  float* out1 = out0 + (size_t)NROW * T5_D;
  float* out2 = out1 + (size_t)T5_H * T5_T * T5_T;

  char* ws = (char*)d_ws;
  size_t off = 0;
  auto alloc = [&](size_t bytes) { char* p = ws + off; off += (bytes + 255) & ~(size_t)255; return p; };
  unsigned short* wqkvT = (unsigned short*)alloc((size_t)2304 * 768 * 2);
  unsigned short* woT   = (unsigned short*)alloc((size_t)768 * 768 * 2);
  unsigned short* wckvT = (unsigned short*)alloc((size_t)1536 * 768 * 2);
  unsigned short* wcqT  = (unsigned short*)alloc((size_t)768 * 768 * 2);
  unsigned short* wcoT  = (unsigned short*)alloc((size_t)768 * 768 * 2);
  unsigned short* wiT   = (unsigned short*)alloc((size_t)3072 * 768 * 2);
  unsigned short* woT2  = (unsigned short*)alloc((size_t)768 * 3072 * 2);
  unsigned short* normb = (unsigned short*)alloc((size_t)NROW * 768 * 2);
  unsigned short* encb  = (unsigned short*)alloc((size_t)NROW * 768 * 2);
  unsigned short* ybuf  = (unsigned short*)alloc((size_t)NROW * 768 * 2);
  unsigned short* cq    = (unsigned short*)alloc((size_t)NROW * 768 * 2);
  float*          attn  = (float*)alloc((size_t)NROW * 768 * 4);
  unsigned char*  rp8p  = (unsigned char*)alloc((size_t)2048 * 2048);
  unsigned short* qkv   = (unsigned short*)alloc((size_t)NROW * 2304 * 2);
  unsigned short* ckv   = (unsigned short*)alloc((size_t)NROW * 1536 * 2);
  unsigned short* vT1   = (unsigned short*)alloc((size_t)24 * 64 * 2048 * 2);
  unsigned short* vT2   = (unsigned short*)alloc((size_t)24 * 64 * 2048 * 2);
  unsigned short* ffh   = (unsigned short*)alloc((size_t)NROW * 3072 * 2);

  dim3 blk(256);

  // prep mega: weight transposes + enc conv + rp pack + rmsnorm1
  {
    PrepArgs pa;
    pa.wsrc[0] = wq;  pa.wdst[0] = wqkvT;
    pa.wsrc[1] = wk;  pa.wdst[1] = wqkvT + 768 * 768;
    pa.wsrc[2] = wvw; pa.wdst[2] = wqkvT + 2 * 768 * 768;
    pa.wsrc[3] = wo;  pa.wdst[3] = woT;
    pa.wsrc[4] = cwk; pa.wdst[4] = wckvT;
    pa.wsrc[5] = cwv; pa.wdst[5] = wckvT + 768 * 768;
    pa.wsrc[6] = cwq; pa.wdst[6] = wcqT;
    pa.wsrc[7] = cwo; pa.wdst[7] = wcoT;
    pa.wsrc[8] = wi;  pa.wdst[8] = wiT;
    pa.wsrc[9] = wo2; pa.wdst[9] = woT2;
    pa.enc = enc; pa.encb = encb; pa.rp = rp; pa.rp8 = rp8p;
    pa.x = x; pa.snw = sn_w; pa.normb = normb;
    prep_kernel<<<17408, blk, 0, stream>>>(pa);
  }

  // stage1 mega: QKV + crossKV GEMMs (V -> vT direct, Q scaled) + pos_bias/out2
  {
    Stage1Args sa;
    sa.normb = normb; sa.wqkvT = wqkvT; sa.encb = encb; sa.wckvT = wckvT;
    sa.qkv = qkv; sa.ckv = ckv; sa.vT1 = vT1; sa.vT2 = vT2;
    sa.rp = rp; sa.rel = rel; sa.out1 = out1; sa.out2 = out2;
    stage1_kernel<<<5056, blk, 0, stream>>>(sa);
  }

  // self-attention (paired q-tiles, bias prefetch, fixed-base exp2 softmax)
  attn_self_kernel<<<dim3(16, 12, 2), blk, 0, stream>>>(qkv, qkv + 768, vT1, rp8p, rel, ybuf);
  // O-proj + residual -> attn (f32)
  gemm_bt<64, 64, 1, 3><<<dim3(12, 64), blk, 0, stream>>>(ybuf, woT, attn, x, 768, 768);

  // cross-attention
  rmsnorm_kernel<<<NROW, blk, 0, stream>>>(attn, cn_w, normb);
  gemm_bt<64, 64, 4, 3><<<dim3(12, 64), blk, 0, stream>>>(normb, wcqT, cq, nullptr, 768, 768);
  attn_cross_kernel<<<dim3(16, 12, 2), blk, 0, stream>>>(cq, ckv, vT2, ybuf);
  gemm_bt<64, 64, 1, 3><<<dim3(12, 64), blk, 0, stream>>>(ybuf, wcoT, attn, attn, 768, 768);

  // FFN
  rmsnorm_kernel<<<NROW, blk, 0, stream>>>(attn, pn_w, normb);
  gemm_bt<128, 128, 2, 2><<<dim3(24, 32), blk, 0, stream>>>(normb, wiT, ffh, nullptr, 3072, 768);
  gemm_bt<64, 64, 1, 3><<<dim3(12, 64), blk, 0, stream>>>(ffh, woT2, out0, attn, 768, 3072);
}

// Round 13
// 340.929 us; speedup vs baseline: 1.0497x; 1.0497x over previous
//
#include <hip/hip_runtime.h>
#include <hip/hip_bf16.h>
#include <stdint.h>

// Problem constants (T5 encoder-decoder block)
#define T5_B   2
#define T5_T   2048
#define T5_S   2048
#define T5_D   768
#define T5_H   12
#define T5_HD  64
#define T5_DFF 3072
#define T5_NB  32
#define NROW   4096   // B*T

#define LOG2E 1.4426950408889634f

typedef __attribute__((ext_vector_type(8))) short bf16x8;
typedef __attribute__((ext_vector_type(4))) short short4v;
typedef __attribute__((ext_vector_type(4))) float f32x4;
typedef __attribute__((ext_vector_type(16))) float f32x16;

__device__ __forceinline__ unsigned short f2bf(float x) {
  unsigned int u = __float_as_uint(x);
  unsigned int r = (u + 0x7FFFu + ((u >> 16) & 1u)) >> 16;   // RNE
  return (unsigned short)r;
}

// 2^x via the native v_exp_f32 (gfx950 v_exp_f32 IS exp2)
__device__ __forceinline__ float fexp2(float x) {
  float d;
  asm("v_exp_f32 %0, %1" : "=v"(d) : "v"(x));
  return d;
}

__device__ __forceinline__ void load_lds16(const void* g, void* l) {
  __builtin_amdgcn_global_load_lds(
      (__attribute__((address_space(1))) void*)(const_cast<void*>(g)),
      (__attribute__((address_space(3))) void*)(l), 16, 0, 0);
}

__device__ __forceinline__ unsigned cvt_pk_bf16(float lo_, float hi_) {
  unsigned d;
  asm("v_cvt_pk_bf16_f32 %0, %1, %2" : "=v"(d) : "v"(lo_), "v"(hi_));
  return d;
}

__device__ __forceinline__ f32x4 mfma16(short4v a, short4v b, f32x4 c) {
#if __has_builtin(__builtin_amdgcn_mfma_f32_16x16x16bf16_1k)
  return __builtin_amdgcn_mfma_f32_16x16x16bf16_1k(a, b, c, 0, 0, 0);
#else
  asm volatile("v_mfma_f32_16x16x16_bf16 %0, %1, %2, %0" : "+v"(c) : "v"(a), "v"(b));
  return c;
#endif
}

// bijective XCD chunk swizzle (m204): 8 XCDs, contiguous chunk per XCD
__device__ __forceinline__ int xcd_swz(int f, int nwg) {
  int q8 = nwg >> 3, r8 = nwg & 7, xcd = f & 7, base = f >> 3;
  return (xcd < r8 ? xcd * (q8 + 1) : r8 * (q8 + 1) + (xcd - r8) * q8) + base;
}

// ---------------------------------------------------------------------------
// GEMM body: C[M][N] = A[M][K](bf16) * Bt[N][K](bf16)^T.
// TM x TN tile, BK=64, XOR-swizzled LDS rows, 4 waves.
// 128x128 tiles: 32x32x16 MFMA. 64x64 tiles: 16x16x32 MFMA.
// NBUF buffering: NBUF=1 -> single-buffer m97 structure (32KB, high occupancy);
// NBUF>=2 -> (NBUF-1)-deep prefetch with counted vmcnt.
// EPI: 0 = bf16 store; 1 = f32 store acc+res; 2 = bf16 relu store;
//      3 = bf16 store w/ cols<qe scaled by LOG2E, cols>=vcol0 -> vT layout;
//      4 = bf16 store scaled by LOG2E.
// ---------------------------------------------------------------------------
template <int TM, int TN, int EPI, int NBUF>
__device__ __forceinline__ void gemm_body(
    int f, int gx, int nwg,
    const unsigned short* __restrict__ A, const unsigned short* __restrict__ Bt,
    void* __restrict__ C, const float* __restrict__ res, int N, int K,
    unsigned short* LDS, unsigned short* vtp = nullptr, int vcol0 = 0, int qe = 0) {
  constexpr bool USE32 = (TM >= 128 && TN >= 128);
  constexpr int WR = (TM >= 128) ? 2 : 1;
  constexpr int WC = 4 / WR;
  constexpr int AM = TM / WR / 16;
  constexpr int AN = TN / WC / 16;
  constexpr int CHA = TM / 8, CHB = TN / 8, CPW = (CHA + CHB) / 4;
  constexpr int BUFSH = (TM + TN) * 64;   // shorts per buffer
  constexpr int DEPTH = NBUF - 1;
  const int tid = threadIdx.x, lane = tid & 63, wv = tid >> 6;
  const int lo = lane & 15, hi = lane >> 4;
  const int l5 = lane >> 5, l31 = lane & 31;
  const int wr = wv / WC, wc = wv % WC;
  const int wg = xcd_swz(f, nwg);
  const int m0 = (wg / gx) * TM, n0 = (wg % gx) * TN;

  f32x4 acc[USE32 ? 1 : AM][USE32 ? 1 : AN];
  f32x16 acc32[USE32 ? 2 : 1][USE32 ? 2 : 1];
  if (USE32) {
#pragma unroll
    for (int i = 0; i < (USE32 ? 2 : 1); ++i)
#pragma unroll
      for (int j = 0; j < (USE32 ? 2 : 1); ++j)
#pragma unroll
        for (int r = 0; r < 16; ++r) acc32[i][j][r] = 0.f;
  } else {
#pragma unroll
    for (int i = 0; i < (USE32 ? 1 : AM); ++i)
#pragma unroll
      for (int j = 0; j < (USE32 ? 1 : AN); ++j) acc[i][j] = f32x4{0.f, 0.f, 0.f, 0.f};
  }

  const int srr  = lane >> 3;                    // row within 8-row chunk
  const int scol = ((lane & 7) ^ srr) * 8;       // pre-swizzled col (halfwords)

  auto stage = [&](int k0, int bsel) {
    unsigned short* Ab = LDS + bsel * BUFSH;
    unsigned short* Bb = Ab + TM * 64;
#pragma unroll
    for (int j = 0; j < CPW; ++j) {
      int c = wv * CPW + j;
      if (c < CHA)
        load_lds16(A + (size_t)(m0 + c * 8 + srr) * K + k0 + scol, Ab + c * 512);
      else {
        int c2 = c - CHA;
        load_lds16(Bt + (size_t)(n0 + c2 * 8 + srr) * K + k0 + scol, Bb + c2 * 512);
      }
    }
  };

  const int nIt = K >> 6;
#pragma unroll
  for (int p = 0; p < DEPTH; ++p)
    if (p < nIt) stage(p << 6, p % NBUF);

  for (int it = 0; it < nIt; ++it) {
    const int bsel = it % NBUF;
    if (NBUF == 1) {
      stage(it << 6, 0);
      asm volatile("s_waitcnt vmcnt(0)" ::: "memory");
    } else if (it + DEPTH < nIt) {
      stage((it + DEPTH) << 6, (it + DEPTH) % NBUF);
      asm volatile("s_waitcnt vmcnt(%0)" :: "n"(DEPTH * CPW) : "memory");
    } else if (it + 1 < nIt) {
      asm volatile("s_waitcnt vmcnt(%0)" :: "n"(CPW) : "memory");
    } else {
      asm volatile("s_waitcnt vmcnt(0)" ::: "memory");
    }
    __builtin_amdgcn_s_barrier();
    __builtin_amdgcn_sched_barrier(0);
    const unsigned short* Ab = LDS + bsel * BUFSH;
    const unsigned short* Bb = Ab + TM * 64;
    if (USE32) {
      // 32x32x16: 4 sub-K of 16; A row = lane&31, k-half = lane>>5
#pragma unroll
      for (int kk = 0; kk < 4; ++kk) {
        bf16x8 af[2], bfr[2];
#pragma unroll
        for (int i = 0; i < 2; ++i) {
          int row = wr * 64 + i * 32 + l31;
          unsigned by = (unsigned)(row * 128) + ((unsigned)(((kk * 2 + l5) ^ (row & 7))) << 4);
          af[i] = *(const bf16x8*)((const char*)Ab + by);
        }
#pragma unroll
        for (int j = 0; j < 2; ++j) {
          int row = wc * 64 + j * 32 + l31;
          unsigned by = (unsigned)(row * 128) + ((unsigned)(((kk * 2 + l5) ^ (row & 7))) << 4);
          bfr[j] = *(const bf16x8*)((const char*)Bb + by);
        }
        __builtin_amdgcn_s_setprio(1);
#pragma unroll
        for (int i = 0; i < 2; ++i)
#pragma unroll
          for (int j = 0; j < 2; ++j)
            acc32[i][j] = __builtin_amdgcn_mfma_f32_32x32x16_bf16(af[i], bfr[j], acc32[i][j], 0, 0, 0);
        __builtin_amdgcn_s_setprio(0);
      }
    } else {
#pragma unroll
      for (int kk = 0; kk < 2; ++kk) {
        bf16x8 af[AM], bfr[AN];
#pragma unroll
        for (int i = 0; i < AM; ++i) {
          int row = wr * (AM * 16) + i * 16 + lo;
          unsigned by = (unsigned)(row * 128) + ((unsigned)(((kk * 4 + hi) ^ (row & 7))) << 4);
          af[i] = *(const bf16x8*)((const char*)Ab + by);
        }
#pragma unroll
        for (int j = 0; j < AN; ++j) {
          int row = wc * (AN * 16) + j * 16 + lo;
          unsigned by = (unsigned)(row * 128) + ((unsigned)(((kk * 4 + hi) ^ (row & 7))) << 4);
          bfr[j] = *(const bf16x8*)((const char*)Bb + by);
        }
        __builtin_amdgcn_s_setprio(1);
#pragma unroll
        for (int i = 0; i < AM; ++i)
#pragma unroll
          for (int j = 0; j < AN; ++j)
            acc[i][j] = __builtin_amdgcn_mfma_f32_16x16x32_bf16(af[i], bfr[j], acc[i][j], 0, 0, 0);
        __builtin_amdgcn_s_setprio(0);
      }
    }
    __builtin_amdgcn_sched_barrier(0);
    __builtin_amdgcn_s_barrier();
  }

  if (USE32) {
    // C/D 32x32: col = lane&31, row = (r&3) + 8*(r>>2) + 4*(lane>>5)
#pragma unroll
    for (int i = 0; i < 2; ++i)
#pragma unroll
      for (int j = 0; j < 2; ++j) {
        int colb = n0 + wc * 64 + j * 32 + l31;
#pragma unroll
        for (int g = 0; g < 4; ++g) {
          int rowb = m0 + wr * 64 + i * 32 + g * 8 + 4 * l5;
          if (EPI == 3 && colb >= vcol0) {
            int cc = colb - vcol0, hh = cc >> 6, dd = cc & 63;
            int bb = rowb >> 11, tt = rowb & 2047;
            unsigned long long pk = (unsigned long long)f2bf(acc32[i][j][g * 4 + 0])
                                  | ((unsigned long long)f2bf(acc32[i][j][g * 4 + 1]) << 16)
                                  | ((unsigned long long)f2bf(acc32[i][j][g * 4 + 2]) << 32)
                                  | ((unsigned long long)f2bf(acc32[i][j][g * 4 + 3]) << 48);
            *(unsigned long long*)(vtp + ((size_t)((bb * 12 + hh) * 64 + dd)) * 2048 + tt) = pk;
          } else {
#pragma unroll
            for (int rr = 0; rr < 4; ++rr) {
              float v = acc32[i][j][g * 4 + rr];
              size_t idx = (size_t)(rowb + rr) * N + colb;
              if (EPI == 3) {
                if (colb < qe) v *= LOG2E;
                ((unsigned short*)C)[idx] = f2bf(v);
              } else if (EPI == 0) {
                ((unsigned short*)C)[idx] = f2bf(v);
              } else if (EPI == 1) {
                ((float*)C)[idx] = v + res[idx];
              } else if (EPI == 2) {
                ((unsigned short*)C)[idx] = f2bf(fmaxf(v, 0.0f));
              } else {
                ((unsigned short*)C)[idx] = f2bf(v * LOG2E);
              }
            }
          }
        }
      }
  } else {
#pragma unroll
    for (int mi = 0; mi < (USE32 ? 1 : AM); ++mi)
#pragma unroll
      for (int ni = 0; ni < (USE32 ? 1 : AN); ++ni) {
        int row = m0 + wr * (AM * 16) + mi * 16 + hi * 4;
        int col = n0 + wc * (AN * 16) + ni * 16 + lo;
#pragma unroll
        for (int r = 0; r < 4; ++r) {
          float v = acc[mi][ni][r];
          size_t idx = (size_t)(row + r) * N + col;
          if (EPI == 0 || EPI == 3) {
            ((unsigned short*)C)[idx] = f2bf(v);
          } else if (EPI == 1) {
            ((float*)C)[idx] = v + res[idx];
          } else if (EPI == 2) {
            ((unsigned short*)C)[idx] = f2bf(fmaxf(v, 0.0f));
          } else {
            ((unsigned short*)C)[idx] = f2bf(v * LOG2E);
          }
        }
      }
  }
}

template <int TM, int TN, int EPI, int NBUF>
__global__ __launch_bounds__(256)
void gemm_bt(const unsigned short* __restrict__ A, const unsigned short* __restrict__ Bt,
             void* __restrict__ C, const float* __restrict__ res, int N, int K) {
  __shared__ __align__(16) unsigned short LDS[NBUF * (TM + TN) * 64];
  int f = blockIdx.y * gridDim.x + blockIdx.x;
  gemm_body<TM, TN, EPI, NBUF>(f, gridDim.x, gridDim.x * gridDim.y, A, Bt, C, res, N, K, LDS);
}

// ---------------------------------------------------------------------------
// Mega prep: 10 weight transposes, enc f32->bf16, rp->u8, rmsnorm1.
// ---------------------------------------------------------------------------
struct PrepArgs {
  const float* wsrc[10];
  unsigned short* wdst[10];
  const float* enc; unsigned short* encb;
  const int* rp; unsigned char* rp8;
  const float* x; const float* snw; unsigned short* normb;
};

__global__ __launch_bounds__(256)
void prep_kernel(PrepArgs a) {
  __shared__ __align__(16) float tile[32][33];
  const int bid = blockIdx.x, tid = threadIdx.x;
  if (bid < 9216) {
    int widx, rem, Kd, Nd;
    if (bid < 4608)      { widx = bid / 576; rem = bid % 576;  Kd = 768;  Nd = 768;  }
    else if (bid < 6912) { widx = 8;         rem = bid - 4608; Kd = 768;  Nd = 3072; }
    else                 { widx = 9;         rem = bid - 6912; Kd = 3072; Nd = 768;  }
    const float* W = a.wsrc[widx];
    unsigned short* Wt = a.wdst[widx];
    int nb = Nd / 32;
    int n0 = (rem % nb) * 32, k0 = (rem / nb) * 32;
    int tx = tid & 31, ty = tid >> 5;
#pragma unroll
    for (int i = 0; i < 32; i += 8)
      tile[ty + i][tx] = W[(size_t)(k0 + ty + i) * Nd + n0 + tx];
    __syncthreads();
#pragma unroll
    for (int i = 0; i < 32; i += 8)
      Wt[(size_t)(n0 + ty + i) * Kd + k0 + tx] = f2bf(tile[tx][ty + i]);
  } else if (bid < 12288) {
    int i = (bid - 9216) * 256 + tid;
    float4 v = ((const float4*)a.enc)[i];
    unsigned long long pk = (unsigned long long)f2bf(v.x)
                          | ((unsigned long long)f2bf(v.y) << 16)
                          | ((unsigned long long)f2bf(v.z) << 32)
                          | ((unsigned long long)f2bf(v.w) << 48);
    *(unsigned long long*)(a.encb + (size_t)i * 4) = pk;
  } else if (bid < 13312) {
    int idx = (bid - 12288) * 256 + tid;          // 16 bytes per thread, identity
    const int4* src = (const int4*)(a.rp + (size_t)idx * 16);
    int4 v0 = src[0], v1 = src[1], v2 = src[2], v3 = src[3];
    uint4 o;
    o.x = (v0.x & 31) | ((v0.y & 31) << 8) | ((v0.z & 31) << 16) | ((v0.w & 31) << 24);
    o.y = (v1.x & 31) | ((v1.y & 31) << 8) | ((v1.z & 31) << 16) | ((v1.w & 31) << 24);
    o.z = (v2.x & 31) | ((v2.y & 31) << 8) | ((v2.z & 31) << 16) | ((v2.w & 31) << 24);
    o.w = (v3.x & 31) | ((v3.y & 31) << 8) | ((v3.z & 31) << 16) | ((v3.w & 31) << 24);
    ((uint4*)a.rp8)[idx] = o;
  } else {
    int row = bid - 13312;
    const float* r = a.x + (size_t)row * 768;
    float x0 = r[tid], x1 = r[tid + 256], x2 = r[tid + 512];
    float s = x0 * x0 + x1 * x1 + x2 * x2;
#pragma unroll
    for (int off = 32; off > 0; off >>= 1) s += __shfl_xor(s, off);
    float* wsm = &tile[0][0];
    int lane = tid & 63, wvv = tid >> 6;
    if (lane == 0) wsm[wvv] = s;
    __syncthreads();
    float tot = wsm[0] + wsm[1] + wsm[2] + wsm[3];
    float rinv = rsqrtf(tot * (1.0f / 768.0f) + 1e-6f);
    unsigned short* o = a.normb + (size_t)row * 768;
    o[tid]       = f2bf(x0 * rinv * a.snw[tid]);
    o[tid + 256] = f2bf(x1 * rinv * a.snw[tid + 256]);
    o[tid + 512] = f2bf(x2 * rinv * a.snw[tid + 512]);
  }
}

// ---------------------------------------------------------------------------
// RMSNorm standalone (stages 2 & 3)
// ---------------------------------------------------------------------------
__global__ __launch_bounds__(256)
void rmsnorm_kernel(const float* __restrict__ in, const float* __restrict__ w,
                    unsigned short* __restrict__ out) {
  int row = blockIdx.x, tid = threadIdx.x;
  const float* r = in + (size_t)row * 768;
  float x0 = r[tid], x1 = r[tid + 256], x2 = r[tid + 512];
  float s = x0 * x0 + x1 * x1 + x2 * x2;
#pragma unroll
  for (int off = 32; off > 0; off >>= 1) s += __shfl_xor(s, off);
  __shared__ float ws_[4];
  int lane = tid & 63, wv = tid >> 6;
  if (lane == 0) ws_[wv] = s;
  __syncthreads();
  float tot = ws_[0] + ws_[1] + ws_[2] + ws_[3];
  float rinv = rsqrtf(tot * (1.0f / 768.0f) + 1e-6f);
  unsigned short* o = out + (size_t)row * 768;
  o[tid]       = f2bf(x0 * rinv * w[tid]);
  o[tid + 256] = f2bf(x1 * rinv * w[tid + 256]);
  o[tid + 512] = f2bf(x2 * rinv * w[tid + 512]);
}

// ---------------------------------------------------------------------------
// Stage-1 mega kernel: QKV GEMM [0,576) (Q cols pre-scaled by LOG2E, V->vT1) +
// crossKV GEMM [576,960) (V->vT2) + pos_bias/out2 [960,5056).
// NBUF=1 (32KB LDS) -> 4-5 blocks/CU (m132 lesson: 64KB was the trap).
// ---------------------------------------------------------------------------
struct Stage1Args {
  const unsigned short *normb, *wqkvT, *encb, *wckvT;
  unsigned short *qkv, *ckv, *vT1, *vT2;
  const int* rp; const float* rel;
  float *out1, *out2;
};

__global__ __launch_bounds__(256)
void stage1_kernel(Stage1Args a) {
  __shared__ __align__(16) unsigned short LDS[16384];
  const int bid = blockIdx.x, tid = threadIdx.x;
  if (bid < 576) {
    gemm_body<128, 128, 3, 1>(bid, 18, 576, a.normb, a.wqkvT, a.qkv, nullptr, 2304, 768,
                              LDS, a.vT1, 1536, 768);
  } else if (bid < 960) {
    gemm_body<128, 128, 3, 1>(bid - 576, 12, 384, a.encb, a.wckvT, a.ckv, nullptr, 1536, 768,
                              LDS, a.vT2, 768, 0);
  } else {
    const int p = bid - 960;
    float* rl = (float*)LDS;
    for (int i = tid; i < 384; i += 256) rl[i] = a.rel[i];
    __syncthreads();
    int t = p >> 1;
    int s = (p & 1) * 1024 + tid * 4;
    int4 nb = *(const int4*)(a.rp + (size_t)t * 2048 + s);
#pragma unroll
    for (int h = 0; h < 12; ++h) {
      float4 v = make_float4(rl[nb.x * 12 + h], rl[nb.y * 12 + h],
                             rl[nb.z * 12 + h], rl[nb.w * 12 + h]);
      *(float4*)(a.out1 + ((size_t)h * 2048 + t) * 2048 + s) = v;
    }
    size_t zbase = ((size_t)p * 256 + tid) * 8;
    float4 z = make_float4(0.f, 0.f, 0.f, 0.f);
    *(float4*)(a.out2 + zbase)     = z;
    *(float4*)(a.out2 + zbase + 4) = z;
  }
}

// ---------------------------------------------------------------------------
// Attention q-tile compute (swapped operands; lane owns q = lane&15).
// FIXED-BASE softmax: p = exp2(s), no max subtraction.
// ---------------------------------------------------------------------------
template <bool SELF>
__device__ __forceinline__ void attn_qcomp(
    const bf16x8& qf0, const bf16x8& qf1, f32x4* Oc, float& l_,
    const unsigned* nb4, const float* rel_l, int qrow, bool edge, int s0,
    const unsigned short* Kb, const unsigned short* Vb, int lo, int hi) {
  f32x4 S[4];
  __builtin_amdgcn_s_setprio(1);
#pragma unroll
  for (int ct = 0; ct < 4; ++ct) {
    int krow = ct * 16 + lo;
    unsigned by0 = ((unsigned)(krow * 128 + hi * 16))      ^ ((unsigned)(krow & 7) << 4);
    unsigned by1 = ((unsigned)(krow * 128 + 64 + hi * 16)) ^ ((unsigned)(krow & 7) << 4);
    bf16x8 kf0 = *(const bf16x8*)((const char*)Kb + by0);
    bf16x8 kf1 = *(const bf16x8*)((const char*)Kb + by1);
    f32x4 sa = f32x4{0.f, 0.f, 0.f, 0.f};
    sa = __builtin_amdgcn_mfma_f32_16x16x32_bf16(kf0, qf0, sa, 0, 0, 0);
    sa = __builtin_amdgcn_mfma_f32_16x16x32_bf16(kf1, qf1, sa, 0, 0, 0);
    S[ct] = sa;
  }
  __builtin_amdgcn_s_setprio(0);

  if constexpr (SELF) {
#pragma unroll
    for (int ct = 0; ct < 4; ++ct) {
#pragma unroll
      for (int r = 0; r < 4; ++r) {
        int s = s0 + ct * 16 + hi * 4 + r;
        float sc = S[ct][r] + rel_l[(nb4[ct] >> (8 * r)) & 31u];
        if (edge && s > qrow) sc = -1e30f;
        S[ct][r] = sc;
      }
    }
  }

  float rs = 0.f;
#pragma unroll
  for (int ct = 0; ct < 4; ++ct)
#pragma unroll
    for (int r = 0; r < 4; ++r) { float e = fexp2(S[ct][r]); S[ct][r] = e; rs += e; }
  l_ += rs;

  short4v pf[4];
#pragma unroll
  for (int ct = 0; ct < 4; ++ct) {
    union { unsigned u[2]; short4v s; } cv;
    cv.u[0] = cvt_pk_bf16(S[ct][0], S[ct][1]);
    cv.u[1] = cvt_pk_bf16(S[ct][2], S[ct][3]);
    pf[ct] = cv.s;
  }

  __builtin_amdgcn_s_setprio(1);
#pragma unroll
  for (int dt = 0; dt < 4; ++dt) {
    int vrow = dt * 16 + lo;
#pragma unroll
    for (int ct = 0; ct < 4; ++ct) {
      unsigned vb = ((unsigned)(vrow * 128 + ct * 32 + hi * 8)) ^ ((unsigned)(vrow & 7) << 4);
      short4v vf = *(const short4v*)((const char*)Vb + vb);
      Oc[dt] = mfma16(vf, pf[ct], Oc[dt]);
    }
  }
  __builtin_amdgcn_s_setprio(0);
}

__device__ __forceinline__ void attn_store(f32x4* Oc, float l_, unsigned short* yr) {
  l_ += __shfl_xor(l_, 16);
  l_ += __shfl_xor(l_, 32);
  float inv = 1.0f / l_;
#pragma unroll
  for (int dt = 0; dt < 4; ++dt) {
    unsigned long long pk = (unsigned long long)f2bf(Oc[dt][0] * inv)
                          | ((unsigned long long)f2bf(Oc[dt][1] * inv) << 16)
                          | ((unsigned long long)f2bf(Oc[dt][2] * inv) << 32)
                          | ((unsigned long long)f2bf(Oc[dt][3] * inv) << 48);
    *(unsigned long long*)(yr + dt * 16) = pk;
  }
}

// ---------------------------------------------------------------------------
// Self-attention: PAIRED q-tiles (i, 31-i). Bias dwords direct from global
// rp8 (L2). grid (16,12,2). LDS 32KB.  [round-10 structure, byte-exact]
// ---------------------------------------------------------------------------
__global__ __launch_bounds__(256)
void attn_self_kernel(const unsigned short* __restrict__ qp,   // qkv, stride 2304
                      const unsigned short* __restrict__ kp,   // qkv+768
                      const unsigned short* __restrict__ vT,
                      const unsigned char* __restrict__ rp8,
                      const float* __restrict__ rel_emb,
                      unsigned short* __restrict__ yp) {
  __shared__ __align__(16) unsigned short Kls[2][4096];
  __shared__ __align__(16) unsigned short Vls[2][4096];
  __shared__ float rel_l[32];

  const int tid = threadIdx.x, lane = tid & 63, wv = tid >> 6;
  const int lo = lane & 15, hi = lane >> 4;
  const int wg = xcd_swz(blockIdx.x + 16 * (blockIdx.y + 12 * blockIdx.z), 384);
  const int xq = wg & 15, h = (wg >> 4) % 12, b = (wg >> 4) / 12;
  const int qta = xq, qtb = 31 - xq;
  const int ntiles = qtb + 1;

  if (tid < 32) rel_l[tid] = rel_emb[tid * 12 + h] * LOG2E;

  const int qA = qta * 64 + wv * 16 + lo;
  const int qB = qtb * 64 + wv * 16 + lo;
  const unsigned short* qrA = qp + (size_t)(b * T5_T + qA) * 2304 + h * 64 + hi * 8;
  const unsigned short* qrB = qp + (size_t)(b * T5_T + qB) * 2304 + h * 64 + hi * 8;
  const bf16x8 qa0 = *(const bf16x8*)qrA;
  const bf16x8 qa1 = *(const bf16x8*)(qrA + 32);
  const bf16x8 qb0 = *(const bf16x8*)qrB;
  const bf16x8 qb1 = *(const bf16x8*)(qrB + 32);
  const unsigned char* rpqA = rp8 + (size_t)qA * 2048 + hi * 4;
  const unsigned char* rpqB = rp8 + (size_t)qB * 2048 + hi * 4;

  f32x4 OA[4], OB[4];
  float lA = 0.f, lB = 0.f;
#pragma unroll
  for (int i = 0; i < 4; ++i) { OA[i] = f32x4{0.f, 0.f, 0.f, 0.f}; OB[i] = f32x4{0.f, 0.f, 0.f, 0.f}; }

  const int krr = lane >> 3;
  const int kd0 = ((lane & 7) ^ krr) * 8;

  auto stage = [&](int kt, int bsel) {
    const int s0 = kt * 64;
#pragma unroll
    for (int j = 0; j < 2; ++j) {
      int c = wv * 2 + j;
      int rr = c * 8 + krr;
      load_lds16(kp + (size_t)(b * 2048 + s0 + rr) * 2304 + h * 64 + kd0, &Kls[bsel][c * 512]);
      load_lds16(vT + (size_t)((b * 12 + h) * 64 + rr) * 2048 + s0 + kd0,  &Vls[bsel][c * 512]);
    }
  };

  stage(0, 0);

  for (int kt = 0; kt < ntiles; ++kt) {
    const int bsel = kt & 1;
    const int s0 = kt * 64;
    asm volatile("s_waitcnt vmcnt(0)" ::: "memory");
    __syncthreads();
    unsigned nbA[4], nbB[4];
    if (kt <= qta) {
#pragma unroll
      for (int ct = 0; ct < 4; ++ct) nbA[ct] = *(const unsigned*)(rpqA + s0 + ct * 16);
    }
#pragma unroll
    for (int ct = 0; ct < 4; ++ct) nbB[ct] = *(const unsigned*)(rpqB + s0 + ct * 16);
    if (kt + 1 < ntiles) stage(kt + 1, bsel ^ 1);

    const unsigned short* Kb = &Kls[bsel][0];
    const unsigned short* Vb = &Vls[bsel][0];

    if (kt <= qta)
      attn_qcomp<true>(qa0, qa1, OA, lA, nbA, rel_l, qA, kt == qta, s0, Kb, Vb, lo, hi);
    attn_qcomp<true>(qb0, qb1, OB, lB, nbB, rel_l, qB, kt == qtb, s0, Kb, Vb, lo, hi);
  }

#if !__has_builtin(__builtin_amdgcn_mfma_f32_16x16x16bf16_1k)
  asm volatile("s_nop 7\n\ts_nop 7" ::: );
#endif

  attn_store(OA, lA, yp + (size_t)(b * T5_T + qA) * 768 + h * 64 + hi * 4);
  attn_store(OB, lB, yp + (size_t)(b * T5_T + qB) * 768 + h * 64 + hi * 4);
}

// ---------------------------------------------------------------------------
// Cross-attention: PAIRED q-tiles (2i, 2i+1), no bias/mask. grid (16,12,2).
// K/V staged once per pair.  [round-10 structure, byte-exact]
// ---------------------------------------------------------------------------
__global__ __launch_bounds__(256)
void attn_cross_kernel(const unsigned short* __restrict__ qp,   // cq, stride 768
                       const unsigned short* __restrict__ kp,   // ckv, stride 1536
                       const unsigned short* __restrict__ vT,
                       unsigned short* __restrict__ yp) {
  __shared__ __align__(16) unsigned short Kls[2][4096];
  __shared__ __align__(16) unsigned short Vls[2][4096];

  const int tid = threadIdx.x, lane = tid & 63, wv = tid >> 6;
  const int lo = lane & 15, hi = lane >> 4;
  const int wg = xcd_swz(blockIdx.x + 16 * (blockIdx.y + 12 * blockIdx.z), 384);
  const int xq = wg & 15, h = (wg >> 4) % 12, b = (wg >> 4) / 12;

  const int qA = (xq * 2) * 64 + wv * 16 + lo;
  const int qB = (xq * 2 + 1) * 64 + wv * 16 + lo;
  const unsigned short* qrA = qp + (size_t)(b * T5_T + qA) * 768 + h * 64 + hi * 8;
  const unsigned short* qrB = qp + (size_t)(b * T5_T + qB) * 768 + h * 64 + hi * 8;
  const bf16x8 qa0 = *(const bf16x8*)qrA;
  const bf16x8 qa1 = *(const bf16x8*)(qrA + 32);
  const bf16x8 qb0 = *(const bf16x8*)qrB;
  const bf16x8 qb1 = *(const bf16x8*)(qrB + 32);

  f32x4 OA[4], OB[4];
  float lA = 0.f, lB = 0.f;
#pragma unroll
  for (int i = 0; i < 4; ++i) { OA[i] = f32x4{0.f, 0.f, 0.f, 0.f}; OB[i] = f32x4{0.f, 0.f, 0.f, 0.f}; }

  const int krr = lane >> 3;
  const int kd0 = ((lane & 7) ^ krr) * 8;

  auto stage = [&](int kt, int bsel) {
    const int s0 = kt * 64;
#pragma unroll
    for (int j = 0; j < 2; ++j) {
      int c = wv * 2 + j;
      int rr = c * 8 + krr;
      load_lds16(kp + (size_t)(b * 2048 + s0 + rr) * 1536 + h * 64 + kd0, &Kls[bsel][c * 512]);
      load_lds16(vT + (size_t)((b * 12 + h) * 64 + rr) * 2048 + s0 + kd0, &Vls[bsel][c * 512]);
    }
  };

  stage(0, 0);

  for (int kt = 0; kt < 32; ++kt) {
    const int bsel = kt & 1;
    asm volatile("s_waitcnt vmcnt(0)" ::: "memory");
    __syncthreads();
    if (kt + 1 < 32) stage(kt + 1, bsel ^ 1);
    const unsigned short* Kb = &Kls[bsel][0];
    const unsigned short* Vb = &Vls[bsel][0];
    attn_qcomp<false>(qa0, qa1, OA, lA, nullptr, nullptr, 0, false, kt * 64, Kb, Vb, lo, hi);
    attn_qcomp<false>(qb0, qb1, OB, lB, nullptr, nullptr, 0, false, kt * 64, Kb, Vb, lo, hi);
  }

#if !__has_builtin(__builtin_amdgcn_mfma_f32_16x16x16bf16_1k)
  asm volatile("s_nop 7\n\ts_nop 7" ::: );
#endif

  attn_store(OA, lA, yp + (size_t)(b * T5_T + qA) * 768 + h * 64 + hi * 4);
  attn_store(OB, lB, yp + (size_t)(b * T5_T + qB) * 768 + h * 64 + hi * 4);
}

// ---------------------------------------------------------------------------
extern "C" void kernel_launch(void* const* d_in, const int* in_sizes, int n_in,
                              void* d_out, int out_size, void* d_ws, size_t ws_size,
                              hipStream_t stream) {
  (void)in_sizes; (void)n_in; (void)out_size; (void)ws_size;
  const float* x    = (const float*)d_in[0];
  const int*   rp   = (const int*)d_in[2];
  const float* enc  = (const float*)d_in[3];
  const float* sn_w = (const float*)d_in[5];
  const float* wq   = (const float*)d_in[6];
  const float* wk   = (const float*)d_in[7];
  const float* wvw  = (const float*)d_in[8];
  const float* wo   = (const float*)d_in[9];
  const float* rel  = (const float*)d_in[10];
  const float* cn_w = (const float*)d_in[11];
  const float* cwq  = (const float*)d_in[12];
  const float* cwk  = (const float*)d_in[13];
  const float* cwv  = (const float*)d_in[14];
  const float* cwo  = (const float*)d_in[15];
  const float* pn_w = (const float*)d_in[16];
  const float* wi   = (const float*)d_in[17];
  const float* wo2  = (const float*)d_in[18];

  float* out0 = (float*)d_out;
  float* out1 = out0 + (size_t)NROW * T5_D;
  float* out2 = out1 + (size_t)T5_H * T5_T * T5_T;

  char* ws = (char*)d_ws;
  size_t off = 0;
  auto alloc = [&](size_t bytes) { char* p = ws + off; off += (bytes + 255) & ~(size_t)255; return p; };
  unsigned short* wqkvT = (unsigned short*)alloc((size_t)2304 * 768 * 2);
  unsigned short* woT   = (unsigned short*)alloc((size_t)768 * 768 * 2);
  unsigned short* wckvT = (unsigned short*)alloc((size_t)1536 * 768 * 2);
  unsigned short* wcqT  = (unsigned short*)alloc((size_t)768 * 768 * 2);
  unsigned short* wcoT  = (unsigned short*)alloc((size_t)768 * 768 * 2);
  unsigned short* wiT   = (unsigned short*)alloc((size_t)3072 * 768 * 2);
  unsigned short* woT2  = (unsigned short*)alloc((size_t)768 * 3072 * 2);
  unsigned short* normb = (unsigned short*)alloc((size_t)NROW * 768 * 2);
  unsigned short* encb  = (unsigned short*)alloc((size_t)NROW * 768 * 2);
  unsigned short* ybuf  = (unsigned short*)alloc((size_t)NROW * 768 * 2);
  unsigned short* cq    = (unsigned short*)alloc((size_t)NROW * 768 * 2);
  float*          attn  = (float*)alloc((size_t)NROW * 768 * 4);
  unsigned char*  rp8p  = (unsigned char*)alloc((size_t)2048 * 2048);
  unsigned short* qkv   = (unsigned short*)alloc((size_t)NROW * 2304 * 2);
  unsigned short* ckv   = (unsigned short*)alloc((size_t)NROW * 1536 * 2);
  unsigned short* vT1   = (unsigned short*)alloc((size_t)24 * 64 * 2048 * 2);
  unsigned short* vT2   = (unsigned short*)alloc((size_t)24 * 64 * 2048 * 2);
  unsigned short* ffh   = (unsigned short*)alloc((size_t)NROW * 3072 * 2);

  dim3 blk(256);

  // prep mega: weight transposes + enc conv + rp pack + rmsnorm1
  {
    PrepArgs pa;
    pa.wsrc[0] = wq;  pa.wdst[0] = wqkvT;
    pa.wsrc[1] = wk;  pa.wdst[1] = wqkvT + 768 * 768;
    pa.wsrc[2] = wvw; pa.wdst[2] = wqkvT + 2 * 768 * 768;
    pa.wsrc[3] = wo;  pa.wdst[3] = woT;
    pa.wsrc[4] = cwk; pa.wdst[4] = wckvT;
    pa.wsrc[5] = cwv; pa.wdst[5] = wckvT + 768 * 768;
    pa.wsrc[6] = cwq; pa.wdst[6] = wcqT;
    pa.wsrc[7] = cwo; pa.wdst[7] = wcoT;
    pa.wsrc[8] = wi;  pa.wdst[8] = wiT;
    pa.wsrc[9] = wo2; pa.wdst[9] = woT2;
    pa.enc = enc; pa.encb = encb; pa.rp = rp; pa.rp8 = rp8p;
    pa.x = x; pa.snw = sn_w; pa.normb = normb;
    prep_kernel<<<17408, blk, 0, stream>>>(pa);
  }

  // stage1 mega: QKV + crossKV GEMMs (V -> vT direct, Q scaled) + pos_bias/out2
  {
    Stage1Args sa;
    sa.normb = normb; sa.wqkvT = wqkvT; sa.encb = encb; sa.wckvT = wckvT;
    sa.qkv = qkv; sa.ckv = ckv; sa.vT1 = vT1; sa.vT2 = vT2;
    sa.rp = rp; sa.rel = rel; sa.out1 = out1; sa.out2 = out2;
    stage1_kernel<<<5056, blk, 0, stream>>>(sa);
  }

  // self-attention (paired q-tiles, global bias reads, fixed-base exp2 softmax)
  attn_self_kernel<<<dim3(16, 12, 2), blk, 0, stream>>>(qkv, qkv + 768, vT1, rp8p, rel, ybuf);
  // O-proj + residual -> attn (f32)
  gemm_bt<64, 64, 1, 3><<<dim3(12, 64), blk, 0, stream>>>(ybuf, woT, attn, x, 768, 768);

  // cross-attention
  rmsnorm_kernel<<<NROW, blk, 0, stream>>>(attn, cn_w, normb);
  gemm_bt<64, 64, 4, 3><<<dim3(12, 64), blk, 0, stream>>>(normb, wcqT, cq, nullptr, 768, 768);
  attn_cross_kernel<<<dim3(16, 12, 2), blk, 0, stream>>>(cq, ckv, vT2, ybuf);
  gemm_bt<64, 64, 1, 3><<<dim3(12, 64), blk, 0, stream>>>(ybuf, wcoT, attn, attn, 768, 768);

  // FFN
  rmsnorm_kernel<<<NROW, blk, 0, stream>>>(attn, pn_w, normb);
  gemm_bt<128, 128, 2, 1><<<dim3(24, 32), blk, 0, stream>>>(normb, wiT, ffh, nullptr, 3072, 768);
  gemm_bt<64, 64, 1, 3><<<dim3(12, 64), blk, 0, stream>>>(ffh, woT2, out0, attn, 768, 3072);
}

// Round 14
// 332.947 us; speedup vs baseline: 1.0748x; 1.0240x over previous
//
#include <hip/hip_runtime.h>
#include <hip/hip_bf16.h>
#include <stdint.h>

// Problem constants (T5 encoder-decoder block)
#define T5_B   2
#define T5_T   2048
#define T5_S   2048
#define T5_D   768
#define T5_H   12
#define T5_HD  64
#define T5_DFF 3072
#define T5_NB  32
#define NROW   4096   // B*T

#define LOG2E 1.4426950408889634f

typedef __attribute__((ext_vector_type(8))) short bf16x8;
typedef __attribute__((ext_vector_type(4))) short short4v;
typedef __attribute__((ext_vector_type(4))) float f32x4;
typedef __attribute__((ext_vector_type(16))) float f32x16;

__device__ __forceinline__ unsigned short f2bf(float x) {
  unsigned int u = __float_as_uint(x);
  unsigned int r = (u + 0x7FFFu + ((u >> 16) & 1u)) >> 16;   // RNE
  return (unsigned short)r;
}

// 2^x via the native v_exp_f32 (gfx950 v_exp_f32 IS exp2)
__device__ __forceinline__ float fexp2(float x) {
  float d;
  asm("v_exp_f32 %0, %1" : "=v"(d) : "v"(x));
  return d;
}

__device__ __forceinline__ void load_lds16(const void* g, void* l) {
  __builtin_amdgcn_global_load_lds(
      (__attribute__((address_space(1))) void*)(const_cast<void*>(g)),
      (__attribute__((address_space(3))) void*)(l), 16, 0, 0);
}

__device__ __forceinline__ unsigned cvt_pk_bf16(float lo_, float hi_) {
  unsigned d;
  asm("v_cvt_pk_bf16_f32 %0, %1, %2" : "=v"(d) : "v"(lo_), "v"(hi_));
  return d;
}

__device__ __forceinline__ f32x4 mfma16(short4v a, short4v b, f32x4 c) {
#if __has_builtin(__builtin_amdgcn_mfma_f32_16x16x16bf16_1k)
  return __builtin_amdgcn_mfma_f32_16x16x16bf16_1k(a, b, c, 0, 0, 0);
#else
  asm volatile("v_mfma_f32_16x16x16_bf16 %0, %1, %2, %0" : "+v"(c) : "v"(a), "v"(b));
  return c;
#endif
}

// bijective XCD chunk swizzle (m204): 8 XCDs, contiguous chunk per XCD
__device__ __forceinline__ int xcd_swz(int f, int nwg) {
  int q8 = nwg >> 3, r8 = nwg & 7, xcd = f & 7, base = f >> 3;
  return (xcd < r8 ? xcd * (q8 + 1) : r8 * (q8 + 1) + (xcd - r8) * q8) + base;
}

// ---------------------------------------------------------------------------
// Weight transpose helper: one 32x32 tile of W[K][N] f32 -> Wt[N][K] bf16
// ---------------------------------------------------------------------------
__device__ __forceinline__ void wtrans_tile(const float* __restrict__ W,
                                            unsigned short* __restrict__ Wt,
                                            int rem, int Kd, int Nd,
                                            float (*tile)[33], int tid) {
  int nb = Nd / 32;
  int n0 = (rem % nb) * 32, k0 = (rem / nb) * 32;
  int tx = tid & 31, ty = tid >> 5;
#pragma unroll
  for (int i = 0; i < 32; i += 8)
    tile[ty + i][tx] = W[(size_t)(k0 + ty + i) * Nd + n0 + tx];
  __syncthreads();
#pragma unroll
  for (int i = 0; i < 32; i += 8)
    Wt[(size_t)(n0 + ty + i) * Kd + k0 + tx] = f2bf(tile[tx][ty + i]);
}

// ---------------------------------------------------------------------------
// GEMM body: C[M][N] = A[M][K](bf16) * Bt[N][K](bf16)^T.
// TM x TN tile, BK=64, XOR-swizzled LDS rows, 4 waves.
// 128x128 tiles: 32x32x16 MFMA. 64x64 tiles: 16x16x32 MFMA.
// NBUF=1 -> single-buffer m97 structure; NBUF>=2 -> counted-vmcnt prefetch.
// EPI: 0 = bf16 store; 1 = f32 store acc+res; 2 = bf16 relu store;
//      3 = bf16 store w/ cols<qe scaled by LOG2E, cols>=vcol0 -> vT layout;
//      4 = bf16 store scaled by LOG2E.
// ---------------------------------------------------------------------------
template <int TM, int TN, int EPI, int NBUF>
__device__ __forceinline__ void gemm_body(
    int f, int gx, int nwg,
    const unsigned short* __restrict__ A, const unsigned short* __restrict__ Bt,
    void* __restrict__ C, const float* __restrict__ res, int N, int K,
    unsigned short* LDS, unsigned short* vtp = nullptr, int vcol0 = 0, int qe = 0) {
  constexpr bool USE32 = (TM >= 128 && TN >= 128);
  constexpr int WR = (TM >= 128) ? 2 : 1;
  constexpr int WC = 4 / WR;
  constexpr int AM = TM / WR / 16;
  constexpr int AN = TN / WC / 16;
  constexpr int CHA = TM / 8, CHB = TN / 8, CPW = (CHA + CHB) / 4;
  constexpr int BUFSH = (TM + TN) * 64;   // shorts per buffer
  constexpr int DEPTH = NBUF - 1;
  const int tid = threadIdx.x, lane = tid & 63, wv = tid >> 6;
  const int lo = lane & 15, hi = lane >> 4;
  const int l5 = lane >> 5, l31 = lane & 31;
  const int wr = wv / WC, wc = wv % WC;
  const int wg = xcd_swz(f, nwg);
  const int m0 = (wg / gx) * TM, n0 = (wg % gx) * TN;

  f32x4 acc[USE32 ? 1 : AM][USE32 ? 1 : AN];
  f32x16 acc32[USE32 ? 2 : 1][USE32 ? 2 : 1];
  if (USE32) {
#pragma unroll
    for (int i = 0; i < (USE32 ? 2 : 1); ++i)
#pragma unroll
      for (int j = 0; j < (USE32 ? 2 : 1); ++j)
#pragma unroll
        for (int r = 0; r < 16; ++r) acc32[i][j][r] = 0.f;
  } else {
#pragma unroll
    for (int i = 0; i < (USE32 ? 1 : AM); ++i)
#pragma unroll
      for (int j = 0; j < (USE32 ? 1 : AN); ++j) acc[i][j] = f32x4{0.f, 0.f, 0.f, 0.f};
  }

  const int srr  = lane >> 3;                    // row within 8-row chunk
  const int scol = ((lane & 7) ^ srr) * 8;       // pre-swizzled col (halfwords)

  auto stage = [&](int k0, int bsel) {
    unsigned short* Ab = LDS + bsel * BUFSH;
    unsigned short* Bb = Ab + TM * 64;
#pragma unroll
    for (int j = 0; j < CPW; ++j) {
      int c = wv * CPW + j;
      if (c < CHA)
        load_lds16(A + (size_t)(m0 + c * 8 + srr) * K + k0 + scol, Ab + c * 512);
      else {
        int c2 = c - CHA;
        load_lds16(Bt + (size_t)(n0 + c2 * 8 + srr) * K + k0 + scol, Bb + c2 * 512);
      }
    }
  };

  const int nIt = K >> 6;
#pragma unroll
  for (int p = 0; p < DEPTH; ++p)
    if (p < nIt) stage(p << 6, p % NBUF);

  for (int it = 0; it < nIt; ++it) {
    const int bsel = it % NBUF;
    if (NBUF == 1) {
      stage(it << 6, 0);
      asm volatile("s_waitcnt vmcnt(0)" ::: "memory");
    } else if (it + DEPTH < nIt) {
      stage((it + DEPTH) << 6, (it + DEPTH) % NBUF);
      asm volatile("s_waitcnt vmcnt(%0)" :: "n"(DEPTH * CPW) : "memory");
    } else if (it + 1 < nIt) {
      asm volatile("s_waitcnt vmcnt(%0)" :: "n"(CPW) : "memory");
    } else {
      asm volatile("s_waitcnt vmcnt(0)" ::: "memory");
    }
    __builtin_amdgcn_s_barrier();
    __builtin_amdgcn_sched_barrier(0);
    const unsigned short* Ab = LDS + bsel * BUFSH;
    const unsigned short* Bb = Ab + TM * 64;
    if (USE32) {
#pragma unroll
      for (int kk = 0; kk < 4; ++kk) {
        bf16x8 af[2], bfr[2];
#pragma unroll
        for (int i = 0; i < 2; ++i) {
          int row = wr * 64 + i * 32 + l31;
          unsigned by = (unsigned)(row * 128) + ((unsigned)(((kk * 2 + l5) ^ (row & 7))) << 4);
          af[i] = *(const bf16x8*)((const char*)Ab + by);
        }
#pragma unroll
        for (int j = 0; j < 2; ++j) {
          int row = wc * 64 + j * 32 + l31;
          unsigned by = (unsigned)(row * 128) + ((unsigned)(((kk * 2 + l5) ^ (row & 7))) << 4);
          bfr[j] = *(const bf16x8*)((const char*)Bb + by);
        }
        __builtin_amdgcn_s_setprio(1);
#pragma unroll
        for (int i = 0; i < 2; ++i)
#pragma unroll
          for (int j = 0; j < 2; ++j)
            acc32[i][j] = __builtin_amdgcn_mfma_f32_32x32x16_bf16(af[i], bfr[j], acc32[i][j], 0, 0, 0);
        __builtin_amdgcn_s_setprio(0);
      }
    } else {
#pragma unroll
      for (int kk = 0; kk < 2; ++kk) {
        bf16x8 af[AM], bfr[AN];
#pragma unroll
        for (int i = 0; i < AM; ++i) {
          int row = wr * (AM * 16) + i * 16 + lo;
          unsigned by = (unsigned)(row * 128) + ((unsigned)(((kk * 4 + hi) ^ (row & 7))) << 4);
          af[i] = *(const bf16x8*)((const char*)Ab + by);
        }
#pragma unroll
        for (int j = 0; j < AN; ++j) {
          int row = wc * (AN * 16) + j * 16 + lo;
          unsigned by = (unsigned)(row * 128) + ((unsigned)(((kk * 4 + hi) ^ (row & 7))) << 4);
          bfr[j] = *(const bf16x8*)((const char*)Bb + by);
        }
        __builtin_amdgcn_s_setprio(1);
#pragma unroll
        for (int i = 0; i < AM; ++i)
#pragma unroll
          for (int j = 0; j < AN; ++j)
            acc[i][j] = __builtin_amdgcn_mfma_f32_16x16x32_bf16(af[i], bfr[j], acc[i][j], 0, 0, 0);
        __builtin_amdgcn_s_setprio(0);
      }
    }
    __builtin_amdgcn_sched_barrier(0);
    __builtin_amdgcn_s_barrier();
  }

  if (USE32) {
    // C/D 32x32: col = lane&31, row = (r&3) + 8*(r>>2) + 4*(lane>>5)
#pragma unroll
    for (int i = 0; i < 2; ++i)
#pragma unroll
      for (int j = 0; j < 2; ++j) {
        int colb = n0 + wc * 64 + j * 32 + l31;
#pragma unroll
        for (int g = 0; g < 4; ++g) {
          int rowb = m0 + wr * 64 + i * 32 + g * 8 + 4 * l5;
          if (EPI == 3 && colb >= vcol0) {
            int cc = colb - vcol0, hh = cc >> 6, dd = cc & 63;
            int bb = rowb >> 11, tt = rowb & 2047;
            unsigned long long pk = (unsigned long long)f2bf(acc32[i][j][g * 4 + 0])
                                  | ((unsigned long long)f2bf(acc32[i][j][g * 4 + 1]) << 16)
                                  | ((unsigned long long)f2bf(acc32[i][j][g * 4 + 2]) << 32)
                                  | ((unsigned long long)f2bf(acc32[i][j][g * 4 + 3]) << 48);
            *(unsigned long long*)(vtp + ((size_t)((bb * 12 + hh) * 64 + dd)) * 2048 + tt) = pk;
          } else {
#pragma unroll
            for (int rr = 0; rr < 4; ++rr) {
              float v = acc32[i][j][g * 4 + rr];
              size_t idx = (size_t)(rowb + rr) * N + colb;
              if (EPI == 3) {
                if (colb < qe) v *= LOG2E;
                ((unsigned short*)C)[idx] = f2bf(v);
              } else if (EPI == 0) {
                ((unsigned short*)C)[idx] = f2bf(v);
              } else if (EPI == 1) {
                ((float*)C)[idx] = v + res[idx];
              } else if (EPI == 2) {
                ((unsigned short*)C)[idx] = f2bf(fmaxf(v, 0.0f));
              } else {
                ((unsigned short*)C)[idx] = f2bf(v * LOG2E);
              }
            }
          }
        }
      }
  } else {
#pragma unroll
    for (int mi = 0; mi < (USE32 ? 1 : AM); ++mi)
#pragma unroll
      for (int ni = 0; ni < (USE32 ? 1 : AN); ++ni) {
        int row = m0 + wr * (AM * 16) + mi * 16 + hi * 4;
        int col = n0 + wc * (AN * 16) + ni * 16 + lo;
#pragma unroll
        for (int r = 0; r < 4; ++r) {
          float v = acc[mi][ni][r];
          size_t idx = (size_t)(row + r) * N + col;
          if (EPI == 0 || EPI == 3) {
            ((unsigned short*)C)[idx] = f2bf(v);
          } else if (EPI == 1) {
            ((float*)C)[idx] = v + res[idx];
          } else if (EPI == 2) {
            ((unsigned short*)C)[idx] = f2bf(fmaxf(v, 0.0f));
          } else {
            ((unsigned short*)C)[idx] = f2bf(v * LOG2E);
          }
        }
      }
  }
}

template <int TM, int TN, int EPI, int NBUF>
__global__ __launch_bounds__(256)
void gemm_bt(const unsigned short* __restrict__ A, const unsigned short* __restrict__ Bt,
             void* __restrict__ C, const float* __restrict__ res, int N, int K) {
  __shared__ __align__(16) unsigned short LDS[NBUF * (TM + TN) * 64];
  int f = blockIdx.y * gridDim.x + blockIdx.x;
  gemm_body<TM, TN, EPI, NBUF>(f, gridDim.x, gridDim.x * gridDim.y, A, Bt, C, res, N, K, LDS);
}

// ---------------------------------------------------------------------------
// Prep (critical-path only): wq,wk,wv,cwk,cwv transposes + enc conv + rmsnorm1.
// [0,2880) 5x 768x768; [2880,5952) enc; [5952,10048) rmsnorm(x).
// ---------------------------------------------------------------------------
struct PrepArgs {
  const float* wsrc[5];
  unsigned short* wdst[5];
  const float* enc; unsigned short* encb;
  const float* x; const float* snw; unsigned short* normb;
};

__global__ __launch_bounds__(256)
void prep_kernel(PrepArgs a) {
  __shared__ __align__(16) float tile[32][33];
  const int bid = blockIdx.x, tid = threadIdx.x;
  if (bid < 2880) {
    int widx = bid / 576, rem = bid % 576;
    wtrans_tile(a.wsrc[widx], a.wdst[widx], rem, 768, 768, tile, tid);
  } else if (bid < 5952) {
    int i = (bid - 2880) * 256 + tid;
    float4 v = ((const float4*)a.enc)[i];
    unsigned long long pk = (unsigned long long)f2bf(v.x)
                          | ((unsigned long long)f2bf(v.y) << 16)
                          | ((unsigned long long)f2bf(v.z) << 32)
                          | ((unsigned long long)f2bf(v.w) << 48);
    *(unsigned long long*)(a.encb + (size_t)i * 4) = pk;
  } else {
    int row = bid - 5952;
    const float* r = a.x + (size_t)row * 768;
    float x0 = r[tid], x1 = r[tid + 256], x2 = r[tid + 512];
    float s = x0 * x0 + x1 * x1 + x2 * x2;
#pragma unroll
    for (int off = 32; off > 0; off >>= 1) s += __shfl_xor(s, off);
    float* wsm = &tile[0][0];
    int lane = tid & 63, wvv = tid >> 6;
    if (lane == 0) wsm[wvv] = s;
    __syncthreads();
    float tot = wsm[0] + wsm[1] + wsm[2] + wsm[3];
    float rinv = rsqrtf(tot * (1.0f / 768.0f) + 1e-6f);
    unsigned short* o = a.normb + (size_t)row * 768;
    o[tid]       = f2bf(x0 * rinv * a.snw[tid]);
    o[tid + 256] = f2bf(x1 * rinv * a.snw[tid + 256]);
    o[tid + 512] = f2bf(x2 * rinv * a.snw[tid + 512]);
  }
}

// ---------------------------------------------------------------------------
// RMSNorm standalone (stages 2 & 3)
// ---------------------------------------------------------------------------
__global__ __launch_bounds__(256)
void rmsnorm_kernel(const float* __restrict__ in, const float* __restrict__ w,
                    unsigned short* __restrict__ out) {
  int row = blockIdx.x, tid = threadIdx.x;
  const float* r = in + (size_t)row * 768;
  float x0 = r[tid], x1 = r[tid + 256], x2 = r[tid + 512];
  float s = x0 * x0 + x1 * x1 + x2 * x2;
#pragma unroll
  for (int off = 32; off > 0; off >>= 1) s += __shfl_xor(s, off);
  __shared__ float ws_[4];
  int lane = tid & 63, wv = tid >> 6;
  if (lane == 0) ws_[wv] = s;
  __syncthreads();
  float tot = ws_[0] + ws_[1] + ws_[2] + ws_[3];
  float rinv = rsqrtf(tot * (1.0f / 768.0f) + 1e-6f);
  unsigned short* o = out + (size_t)row * 768;
  o[tid]       = f2bf(x0 * rinv * w[tid]);
  o[tid + 256] = f2bf(x1 * rinv * w[tid + 256]);
  o[tid + 512] = f2bf(x2 * rinv * w[tid + 512]);
}

// ---------------------------------------------------------------------------
// Stage-1 mega kernel:
// [0,576) QKV GEMM (Q scaled LOG2E, V->vT1); [576,960) crossKV GEMM (V->vT2);
// [960,5056) pos_bias/out2; [5056,...) deferred prep: wo,cwq,cwo,wi,wo2,rp8.
// ---------------------------------------------------------------------------
struct Stage1Args {
  const unsigned short *normb, *wqkvT, *encb, *wckvT;
  unsigned short *qkv, *ckv, *vT1, *vT2;
  const int* rp; const float* rel;
  float *out1, *out2;
  const float *wo, *cwq, *cwo, *wi, *wo2;
  unsigned short *woT, *wcqT, *wcoT, *wiT, *woT2;
  unsigned char* rp8;
};

__global__ __launch_bounds__(256)
void stage1_kernel(Stage1Args a) {
  __shared__ __align__(16) unsigned short LDS[16384];
  const int bid = blockIdx.x, tid = threadIdx.x;
  if (bid < 576) {
    gemm_body<128, 128, 3, 1>(bid, 18, 576, a.normb, a.wqkvT, a.qkv, nullptr, 2304, 768,
                              LDS, a.vT1, 1536, 768);
  } else if (bid < 960) {
    gemm_body<128, 128, 3, 1>(bid - 576, 12, 384, a.encb, a.wckvT, a.ckv, nullptr, 1536, 768,
                              LDS, a.vT2, 768, 0);
  } else if (bid < 5056) {
    const int p = bid - 960;
    float* rl = (float*)LDS;
    for (int i = tid; i < 384; i += 256) rl[i] = a.rel[i];
    __syncthreads();
    int t = p >> 1;
    int s = (p & 1) * 1024 + tid * 4;
    int4 nb = *(const int4*)(a.rp + (size_t)t * 2048 + s);
#pragma unroll
    for (int h = 0; h < 12; ++h) {
      float4 v = make_float4(rl[nb.x * 12 + h], rl[nb.y * 12 + h],
                             rl[nb.z * 12 + h], rl[nb.w * 12 + h]);
      *(float4*)(a.out1 + ((size_t)h * 2048 + t) * 2048 + s) = v;
    }
    size_t zbase = ((size_t)p * 256 + tid) * 8;
    float4 z = make_float4(0.f, 0.f, 0.f, 0.f);
    *(float4*)(a.out2 + zbase)     = z;
    *(float4*)(a.out2 + zbase + 4) = z;
  } else if (bid < 5632) {
    wtrans_tile(a.wo,  a.woT,  bid - 5056, 768, 768, (float(*)[33])LDS, tid);
  } else if (bid < 6208) {
    wtrans_tile(a.cwq, a.wcqT, bid - 5632, 768, 768, (float(*)[33])LDS, tid);
  } else if (bid < 6784) {
    wtrans_tile(a.cwo, a.wcoT, bid - 6208, 768, 768, (float(*)[33])LDS, tid);
  } else if (bid < 9088) {
    wtrans_tile(a.wi,  a.wiT,  bid - 6784, 768, 3072, (float(*)[33])LDS, tid);
  } else if (bid < 11392) {
    wtrans_tile(a.wo2, a.woT2, bid - 9088, 3072, 768, (float(*)[33])LDS, tid);
  } else {
    int idx = (bid - 11392) * 256 + tid;          // 16 ints -> 16 bytes per thread
    const int4* src = (const int4*)(a.rp + (size_t)idx * 16);
    int4 v0 = src[0], v1 = src[1], v2 = src[2], v3 = src[3];
    uint4 o;
    o.x = (v0.x & 31) | ((v0.y & 31) << 8) | ((v0.z & 31) << 16) | ((v0.w & 31) << 24);
    o.y = (v1.x & 31) | ((v1.y & 31) << 8) | ((v1.z & 31) << 16) | ((v1.w & 31) << 24);
    o.z = (v2.x & 31) | ((v2.y & 31) << 8) | ((v2.z & 31) << 16) | ((v2.w & 31) << 24);
    o.w = (v3.x & 31) | ((v3.y & 31) << 8) | ((v3.z & 31) << 16) | ((v3.w & 31) << 24);
    ((uint4*)a.rp8)[idx] = o;
  }
}

// ---------------------------------------------------------------------------
// PAIRED attention tile compute: both q-sets share K/V fragment loads.
// FIXED-BASE softmax: p = exp2(s), no max subtraction. doA = A-side active
// (wave-uniform). SELF adds rel bias + causal edge mask.
// ---------------------------------------------------------------------------
template <bool SELF>
__device__ __forceinline__ void attn_qcomp2(
    const bf16x8& qa0, const bf16x8& qa1, const bf16x8& qb0, const bf16x8& qb1,
    f32x4* OA, f32x4* OB, float& lA, float& lB,
    const unsigned* nbA, const unsigned* nbB, const float* rel_l,
    int qA, int qB, bool doA, bool edgeA, bool edgeB, int s0,
    const unsigned short* Kb, const unsigned short* Vb, int lo, int hi) {
  f32x4 SA[4], SB[4];
  __builtin_amdgcn_s_setprio(1);
#pragma unroll
  for (int ct = 0; ct < 4; ++ct) {
    int krow = ct * 16 + lo;
    unsigned by0 = ((unsigned)(krow * 128 + hi * 16))      ^ ((unsigned)(krow & 7) << 4);
    unsigned by1 = ((unsigned)(krow * 128 + 64 + hi * 16)) ^ ((unsigned)(krow & 7) << 4);
    bf16x8 kf0 = *(const bf16x8*)((const char*)Kb + by0);
    bf16x8 kf1 = *(const bf16x8*)((const char*)Kb + by1);
    if (!SELF || doA) {
      f32x4 sa = f32x4{0.f, 0.f, 0.f, 0.f};
      sa = __builtin_amdgcn_mfma_f32_16x16x32_bf16(kf0, qa0, sa, 0, 0, 0);
      sa = __builtin_amdgcn_mfma_f32_16x16x32_bf16(kf1, qa1, sa, 0, 0, 0);
      SA[ct] = sa;
    }
    f32x4 sb = f32x4{0.f, 0.f, 0.f, 0.f};
    sb = __builtin_amdgcn_mfma_f32_16x16x32_bf16(kf0, qb0, sb, 0, 0, 0);
    sb = __builtin_amdgcn_mfma_f32_16x16x32_bf16(kf1, qb1, sb, 0, 0, 0);
    SB[ct] = sb;
  }
  __builtin_amdgcn_s_setprio(0);

  if constexpr (SELF) {
    if (doA) {
#pragma unroll
      for (int ct = 0; ct < 4; ++ct)
#pragma unroll
        for (int r = 0; r < 4; ++r) {
          int s = s0 + ct * 16 + hi * 4 + r;
          float sc = SA[ct][r] + rel_l[(nbA[ct] >> (8 * r)) & 31u];
          if (edgeA && s > qA) sc = -1e30f;
          SA[ct][r] = sc;
        }
    }
#pragma unroll
    for (int ct = 0; ct < 4; ++ct)
#pragma unroll
      for (int r = 0; r < 4; ++r) {
        int s = s0 + ct * 16 + hi * 4 + r;
        float sc = SB[ct][r] + rel_l[(nbB[ct] >> (8 * r)) & 31u];
        if (edgeB && s > qB) sc = -1e30f;
        SB[ct][r] = sc;
      }
  }

  short4v pfA[4], pfB[4];
  if (!SELF || doA) {
    float rs = 0.f;
#pragma unroll
    for (int ct = 0; ct < 4; ++ct)
#pragma unroll
      for (int r = 0; r < 4; ++r) { float e = fexp2(SA[ct][r]); SA[ct][r] = e; rs += e; }
    lA += rs;
#pragma unroll
    for (int ct = 0; ct < 4; ++ct) {
      union { unsigned u[2]; short4v s; } cv;
      cv.u[0] = cvt_pk_bf16(SA[ct][0], SA[ct][1]);
      cv.u[1] = cvt_pk_bf16(SA[ct][2], SA[ct][3]);
      pfA[ct] = cv.s;
    }
  }
  {
    float rs = 0.f;
#pragma unroll
    for (int ct = 0; ct < 4; ++ct)
#pragma unroll
      for (int r = 0; r < 4; ++r) { float e = fexp2(SB[ct][r]); SB[ct][r] = e; rs += e; }
    lB += rs;
#pragma unroll
    for (int ct = 0; ct < 4; ++ct) {
      union { unsigned u[2]; short4v s; } cv;
      cv.u[0] = cvt_pk_bf16(SB[ct][0], SB[ct][1]);
      cv.u[1] = cvt_pk_bf16(SB[ct][2], SB[ct][3]);
      pfB[ct] = cv.s;
    }
  }

  __builtin_amdgcn_s_setprio(1);
#pragma unroll
  for (int dt = 0; dt < 4; ++dt) {
    int vrow = dt * 16 + lo;
    short4v vf[4];
#pragma unroll
    for (int ct = 0; ct < 4; ++ct) {
      unsigned vb = ((unsigned)(vrow * 128 + ct * 32 + hi * 8)) ^ ((unsigned)(vrow & 7) << 4);
      vf[ct] = *(const short4v*)((const char*)Vb + vb);
    }
    if (!SELF || doA) {
#pragma unroll
      for (int ct = 0; ct < 4; ++ct) OA[dt] = mfma16(vf[ct], pfA[ct], OA[dt]);
    }
#pragma unroll
    for (int ct = 0; ct < 4; ++ct) OB[dt] = mfma16(vf[ct], pfB[ct], OB[dt]);
  }
  __builtin_amdgcn_s_setprio(0);
}

__device__ __forceinline__ void attn_store(f32x4* Oc, float l_, unsigned short* yr) {
  l_ += __shfl_xor(l_, 16);
  l_ += __shfl_xor(l_, 32);
  float inv = 1.0f / l_;
#pragma unroll
  for (int dt = 0; dt < 4; ++dt) {
    unsigned long long pk = (unsigned long long)f2bf(Oc[dt][0] * inv)
                          | ((unsigned long long)f2bf(Oc[dt][1] * inv) << 16)
                          | ((unsigned long long)f2bf(Oc[dt][2] * inv) << 32)
                          | ((unsigned long long)f2bf(Oc[dt][3] * inv) << 48);
    *(unsigned long long*)(yr + dt * 16) = pk;
  }
}

// ---------------------------------------------------------------------------
// Self-attention: PAIRED q-tiles (i, 31-i), shared K/V fragment loads.
// Bias dwords direct from global rp8 (L2). grid (16,12,2). LDS 32KB.
// ---------------------------------------------------------------------------
__global__ __launch_bounds__(256)
void attn_self_kernel(const unsigned short* __restrict__ qp,   // qkv, stride 2304
                      const unsigned short* __restrict__ kp,   // qkv+768
                      const unsigned short* __restrict__ vT,
                      const unsigned char* __restrict__ rp8,
                      const float* __restrict__ rel_emb,
                      unsigned short* __restrict__ yp) {
  __shared__ __align__(16) unsigned short Kls[2][4096];
  __shared__ __align__(16) unsigned short Vls[2][4096];
  __shared__ float rel_l[32];

  const int tid = threadIdx.x, lane = tid & 63, wv = tid >> 6;
  const int lo = lane & 15, hi = lane >> 4;
  const int wg = xcd_swz(blockIdx.x + 16 * (blockIdx.y + 12 * blockIdx.z), 384);
  const int xq = wg & 15, h = (wg >> 4) % 12, b = (wg >> 4) / 12;
  const int qta = xq, qtb = 31 - xq;
  const int ntiles = qtb + 1;

  if (tid < 32) rel_l[tid] = rel_emb[tid * 12 + h] * LOG2E;

  const int qA = qta * 64 + wv * 16 + lo;
  const int qB = qtb * 64 + wv * 16 + lo;
  const unsigned short* qrA = qp + (size_t)(b * T5_T + qA) * 2304 + h * 64 + hi * 8;
  const unsigned short* qrB = qp + (size_t)(b * T5_T + qB) * 2304 + h * 64 + hi * 8;
  const bf16x8 qa0 = *(const bf16x8*)qrA;
  const bf16x8 qa1 = *(const bf16x8*)(qrA + 32);
  const bf16x8 qb0 = *(const bf16x8*)qrB;
  const bf16x8 qb1 = *(const bf16x8*)(qrB + 32);
  const unsigned char* rpqA = rp8 + (size_t)qA * 2048 + hi * 4;
  const unsigned char* rpqB = rp8 + (size_t)qB * 2048 + hi * 4;

  f32x4 OA[4], OB[4];
  float lA = 0.f, lB = 0.f;
#pragma unroll
  for (int i = 0; i < 4; ++i) { OA[i] = f32x4{0.f, 0.f, 0.f, 0.f}; OB[i] = f32x4{0.f, 0.f, 0.f, 0.f}; }

  const int krr = lane >> 3;
  const int kd0 = ((lane & 7) ^ krr) * 8;

  auto stage = [&](int kt, int bsel) {
    const int s0 = kt * 64;
#pragma unroll
    for (int j = 0; j < 2; ++j) {
      int c = wv * 2 + j;
      int rr = c * 8 + krr;
      load_lds16(kp + (size_t)(b * 2048 + s0 + rr) * 2304 + h * 64 + kd0, &Kls[bsel][c * 512]);
      load_lds16(vT + (size_t)((b * 12 + h) * 64 + rr) * 2048 + s0 + kd0,  &Vls[bsel][c * 512]);
    }
  };

  stage(0, 0);

  for (int kt = 0; kt < ntiles; ++kt) {
    const int bsel = kt & 1;
    const int s0 = kt * 64;
    asm volatile("s_waitcnt vmcnt(0)" ::: "memory");
    __syncthreads();
    const bool doA = (kt <= qta);
    unsigned nbA[4], nbB[4];
    if (doA) {
#pragma unroll
      for (int ct = 0; ct < 4; ++ct) nbA[ct] = *(const unsigned*)(rpqA + s0 + ct * 16);
    }
#pragma unroll
    for (int ct = 0; ct < 4; ++ct) nbB[ct] = *(const unsigned*)(rpqB + s0 + ct * 16);
    if (kt + 1 < ntiles) stage(kt + 1, bsel ^ 1);

    attn_qcomp2<true>(qa0, qa1, qb0, qb1, OA, OB, lA, lB, nbA, nbB, rel_l,
                      qA, qB, doA, kt == qta, kt == qtb, s0,
                      &Kls[bsel][0], &Vls[bsel][0], lo, hi);
  }

#if !__has_builtin(__builtin_amdgcn_mfma_f32_16x16x16bf16_1k)
  asm volatile("s_nop 7\n\ts_nop 7" ::: );
#endif

  attn_store(OA, lA, yp + (size_t)(b * T5_T + qA) * 768 + h * 64 + hi * 4);
  attn_store(OB, lB, yp + (size_t)(b * T5_T + qB) * 768 + h * 64 + hi * 4);
}

// ---------------------------------------------------------------------------
// Cross-attention: PAIRED q-tiles (2i, 2i+1), shared K/V fragment loads.
// grid (16,12,2). LDS 32KB.
// ---------------------------------------------------------------------------
__global__ __launch_bounds__(256)
void attn_cross_kernel(const unsigned short* __restrict__ qp,   // cq, stride 768
                       const unsigned short* __restrict__ kp,   // ckv, stride 1536
                       const unsigned short* __restrict__ vT,
                       unsigned short* __restrict__ yp) {
  __shared__ __align__(16) unsigned short Kls[2][4096];
  __shared__ __align__(16) unsigned short Vls[2][4096];

  const int tid = threadIdx.x, lane = tid & 63, wv = tid >> 6;
  const int lo = lane & 15, hi = lane >> 4;
  const int wg = xcd_swz(blockIdx.x + 16 * (blockIdx.y + 12 * blockIdx.z), 384);
  const int xq = wg & 15, h = (wg >> 4) % 12, b = (wg >> 4) / 12;

  const int qA = (xq * 2) * 64 + wv * 16 + lo;
  const int qB = (xq * 2 + 1) * 64 + wv * 16 + lo;
  const unsigned short* qrA = qp + (size_t)(b * T5_T + qA) * 768 + h * 64 + hi * 8;
  const unsigned short* qrB = qp + (size_t)(b * T5_T + qB) * 768 + h * 64 + hi * 8;
  const bf16x8 qa0 = *(const bf16x8*)qrA;
  const bf16x8 qa1 = *(const bf16x8*)(qrA + 32);
  const bf16x8 qb0 = *(const bf16x8*)qrB;
  const bf16x8 qb1 = *(const bf16x8*)(qrB + 32);

  f32x4 OA[4], OB[4];
  float lA = 0.f, lB = 0.f;
#pragma unroll
  for (int i = 0; i < 4; ++i) { OA[i] = f32x4{0.f, 0.f, 0.f, 0.f}; OB[i] = f32x4{0.f, 0.f, 0.f, 0.f}; }

  const int krr = lane >> 3;
  const int kd0 = ((lane & 7) ^ krr) * 8;

  auto stage = [&](int kt, int bsel) {
    const int s0 = kt * 64;
#pragma unroll
    for (int j = 0; j < 2; ++j) {
      int c = wv * 2 + j;
      int rr = c * 8 + krr;
      load_lds16(kp + (size_t)(b * 2048 + s0 + rr) * 1536 + h * 64 + kd0, &Kls[bsel][c * 512]);
      load_lds16(vT + (size_t)((b * 12 + h) * 64 + rr) * 2048 + s0 + kd0, &Vls[bsel][c * 512]);
    }
  };

  stage(0, 0);

  for (int kt = 0; kt < 32; ++kt) {
    const int bsel = kt & 1;
    asm volatile("s_waitcnt vmcnt(0)" ::: "memory");
    __syncthreads();
    if (kt + 1 < 32) stage(kt + 1, bsel ^ 1);
    attn_qcomp2<false>(qa0, qa1, qb0, qb1, OA, OB, lA, lB, nullptr, nullptr, nullptr,
                       0, 0, true, false, false, kt * 64,
                       &Kls[bsel][0], &Vls[bsel][0], lo, hi);
  }

#if !__has_builtin(__builtin_amdgcn_mfma_f32_16x16x16bf16_1k)
  asm volatile("s_nop 7\n\ts_nop 7" ::: );
#endif

  attn_store(OA, lA, yp + (size_t)(b * T5_T + qA) * 768 + h * 64 + hi * 4);
  attn_store(OB, lB, yp + (size_t)(b * T5_T + qB) * 768 + h * 64 + hi * 4);
}

// ---------------------------------------------------------------------------
extern "C" void kernel_launch(void* const* d_in, const int* in_sizes, int n_in,
                              void* d_out, int out_size, void* d_ws, size_t ws_size,
                              hipStream_t stream) {
  (void)in_sizes; (void)n_in; (void)out_size; (void)ws_size;
  const float* x    = (const float*)d_in[0];
  const int*   rp   = (const int*)d_in[2];
  const float* enc  = (const float*)d_in[3];
  const float* sn_w = (const float*)d_in[5];
  const float* wq   = (const float*)d_in[6];
  const float* wk   = (const float*)d_in[7];
  const float* wvw  = (const float*)d_in[8];
  const float* wo   = (const float*)d_in[9];
  const float* rel  = (const float*)d_in[10];
  const float* cn_w = (const float*)d_in[11];
  const float* cwq  = (const float*)d_in[12];
  const float* cwk  = (const float*)d_in[13];
  const float* cwv  = (const float*)d_in[14];
  const float* cwo  = (const float*)d_in[15];
  const float* pn_w = (const float*)d_in[16];
  const float* wi   = (const float*)d_in[17];
  const float* wo2  = (const float*)d_in[18];

  float* out0 = (float*)d_out;
  float* out1 = out0 + (size_t)NROW * T5_D;
  float* out2 = out1 + (size_t)T5_H * T5_T * T5_T;

  char* ws = (char*)d_ws;
  size_t off = 0;
  auto alloc = [&](size_t bytes) { char* p = ws + off; off += (bytes + 255) & ~(size_t)255; return p; };
  unsigned short* wqkvT = (unsigned short*)alloc((size_t)2304 * 768 * 2);
  unsigned short* woT   = (unsigned short*)alloc((size_t)768 * 768 * 2);
  unsigned short* wckvT = (unsigned short*)alloc((size_t)1536 * 768 * 2);
  unsigned short* wcqT  = (unsigned short*)alloc((size_t)768 * 768 * 2);
  unsigned short* wcoT  = (unsigned short*)alloc((size_t)768 * 768 * 2);
  unsigned short* wiT   = (unsigned short*)alloc((size_t)3072 * 768 * 2);
  unsigned short* woT2  = (unsigned short*)alloc((size_t)768 * 3072 * 2);
  unsigned short* normb = (unsigned short*)alloc((size_t)NROW * 768 * 2);
  unsigned short* encb  = (unsigned short*)alloc((size_t)NROW * 768 * 2);
  unsigned short* ybuf  = (unsigned short*)alloc((size_t)NROW * 768 * 2);
  unsigned short* cq    = (unsigned short*)alloc((size_t)NROW * 768 * 2);
  float*          attn  = (float*)alloc((size_t)NROW * 768 * 4);
  unsigned char*  rp8p  = (unsigned char*)alloc((size_t)2048 * 2048);
  unsigned short* qkv   = (unsigned short*)alloc((size_t)NROW * 2304 * 2);
  unsigned short* ckv   = (unsigned short*)alloc((size_t)NROW * 1536 * 2);
  unsigned short* vT1   = (unsigned short*)alloc((size_t)24 * 64 * 2048 * 2);
  unsigned short* vT2   = (unsigned short*)alloc((size_t)24 * 64 * 2048 * 2);
  unsigned short* ffh   = (unsigned short*)alloc((size_t)NROW * 3072 * 2);

  dim3 blk(256);

  // prep (critical-path only): wq/wk/wv/cwk/cwv + enc conv + rmsnorm1
  {
    PrepArgs pa;
    pa.wsrc[0] = wq;  pa.wdst[0] = wqkvT;
    pa.wsrc[1] = wk;  pa.wdst[1] = wqkvT + 768 * 768;
    pa.wsrc[2] = wvw; pa.wdst[2] = wqkvT + 2 * 768 * 768;
    pa.wsrc[3] = cwk; pa.wdst[3] = wckvT;
    pa.wsrc[4] = cwv; pa.wdst[4] = wckvT + 768 * 768;
    pa.enc = enc; pa.encb = encb;
    pa.x = x; pa.snw = sn_w; pa.normb = normb;
    prep_kernel<<<10048, blk, 0, stream>>>(pa);
  }

  // stage1 mega: QKV+crossKV GEMMs + pos_bias/out2 + deferred weight prep
  {
    Stage1Args sa;
    sa.normb = normb; sa.wqkvT = wqkvT; sa.encb = encb; sa.wckvT = wckvT;
    sa.qkv = qkv; sa.ckv = ckv; sa.vT1 = vT1; sa.vT2 = vT2;
    sa.rp = rp; sa.rel = rel; sa.out1 = out1; sa.out2 = out2;
    sa.wo = wo; sa.cwq = cwq; sa.cwo = cwo; sa.wi = wi; sa.wo2 = wo2;
    sa.woT = woT; sa.wcqT = wcqT; sa.wcoT = wcoT; sa.wiT = wiT; sa.woT2 = woT2;
    sa.rp8 = rp8p;
    stage1_kernel<<<12416, blk, 0, stream>>>(sa);
  }

  // self-attention (paired q-tiles, shared frag loads, exp2 softmax)
  attn_self_kernel<<<dim3(16, 12, 2), blk, 0, stream>>>(qkv, qkv + 768, vT1, rp8p, rel, ybuf);
  // O-proj + residual -> attn (f32)
  gemm_bt<64, 64, 1, 3><<<dim3(12, 64), blk, 0, stream>>>(ybuf, woT, attn, x, 768, 768);

  // cross-attention
  rmsnorm_kernel<<<NROW, blk, 0, stream>>>(attn, cn_w, normb);
  gemm_bt<64, 64, 4, 3><<<dim3(12, 64), blk, 0, stream>>>(normb, wcqT, cq, nullptr, 768, 768);
  attn_cross_kernel<<<dim3(16, 12, 2), blk, 0, stream>>>(cq, ckv, vT2, ybuf);
  gemm_bt<64, 64, 1, 3><<<dim3(12, 64), blk, 0, stream>>>(ybuf, wcoT, attn, attn, 768, 768);

  // FFN
  rmsnorm_kernel<<<NROW, blk, 0, stream>>>(attn, pn_w, normb);
  gemm_bt<128, 128, 2, 1><<<dim3(24, 32), blk, 0, stream>>>(normb, wiT, ffh, nullptr, 3072, 768);
  gemm_bt<64, 64, 1, 3><<<dim3(12, 64), blk, 0, stream>>>(ffh, woT2, out0, attn, 768, 3072);
}

// Round 15
// 318.793 us; speedup vs baseline: 1.1226x; 1.0444x over previous
//
#include <hip/hip_runtime.h>
#include <hip/hip_bf16.h>
#include <stdint.h>

// Problem constants (T5 encoder-decoder block)
#define T5_B   2
#define T5_T   2048
#define T5_S   2048
#define T5_D   768
#define T5_H   12
#define T5_HD  64
#define T5_DFF 3072
#define T5_NB  32
#define NROW   4096   // B*T

#define LOG2E 1.4426950408889634f

typedef __attribute__((ext_vector_type(8))) short bf16x8;
typedef __attribute__((ext_vector_type(4))) short short4v;
typedef __attribute__((ext_vector_type(4))) float f32x4;
typedef __attribute__((ext_vector_type(16))) float f32x16;

__device__ __forceinline__ unsigned short f2bf(float x) {
  unsigned int u = __float_as_uint(x);
  unsigned int r = (u + 0x7FFFu + ((u >> 16) & 1u)) >> 16;   // RNE
  return (unsigned short)r;
}

// 2^x via the native v_exp_f32 (gfx950 v_exp_f32 IS exp2)
__device__ __forceinline__ float fexp2(float x) {
  float d;
  asm("v_exp_f32 %0, %1" : "=v"(d) : "v"(x));
  return d;
}

__device__ __forceinline__ void load_lds16(const void* g, void* l) {
  __builtin_amdgcn_global_load_lds(
      (__attribute__((address_space(1))) void*)(const_cast<void*>(g)),
      (__attribute__((address_space(3))) void*)(l), 16, 0, 0);
}

__device__ __forceinline__ unsigned cvt_pk_bf16(float lo_, float hi_) {
  unsigned d;
  asm("v_cvt_pk_bf16_f32 %0, %1, %2" : "=v"(d) : "v"(lo_), "v"(hi_));
  return d;
}

__device__ __forceinline__ f32x4 mfma16(short4v a, short4v b, f32x4 c) {
#if __has_builtin(__builtin_amdgcn_mfma_f32_16x16x16bf16_1k)
  return __builtin_amdgcn_mfma_f32_16x16x16bf16_1k(a, b, c, 0, 0, 0);
#else
  asm volatile("v_mfma_f32_16x16x16_bf16 %0, %1, %2, %0" : "+v"(c) : "v"(a), "v"(b));
  return c;
#endif
}

// bijective XCD chunk swizzle (m204): 8 XCDs, contiguous chunk per XCD
__device__ __forceinline__ int xcd_swz(int f, int nwg) {
  int q8 = nwg >> 3, r8 = nwg & 7, xcd = f & 7, base = f >> 3;
  return (xcd < r8 ? xcd * (q8 + 1) : r8 * (q8 + 1) + (xcd - r8) * q8) + base;
}

// ---------------------------------------------------------------------------
// Weight transpose helper: one 32x32 tile of W[K][N] f32 -> Wt[N][K] bf16
// ---------------------------------------------------------------------------
__device__ __forceinline__ void wtrans_tile(const float* __restrict__ W,
                                            unsigned short* __restrict__ Wt,
                                            int rem, int Kd, int Nd,
                                            float (*tile)[33], int tid) {
  int nb = Nd / 32;
  int n0 = (rem % nb) * 32, k0 = (rem / nb) * 32;
  int tx = tid & 31, ty = tid >> 5;
#pragma unroll
  for (int i = 0; i < 32; i += 8)
    tile[ty + i][tx] = W[(size_t)(k0 + ty + i) * Nd + n0 + tx];
  __syncthreads();
#pragma unroll
  for (int i = 0; i < 32; i += 8)
    Wt[(size_t)(n0 + ty + i) * Kd + k0 + tx] = f2bf(tile[tx][ty + i]);
}

// ---------------------------------------------------------------------------
// GEMM body: C[M][N] = A[M][K](bf16) * Bt[N][K](bf16)^T.
// TM x TN tile, BK=64, XOR-swizzled LDS rows, 4 waves.
// 128x128 tiles: 32x32x16 MFMA. 64x64 tiles: 16x16x32 MFMA.
// NBUF=1 -> single-buffer m97 structure; NBUF>=2 -> counted-vmcnt prefetch.
// EPI: 0 = bf16 store; 1 = f32 store acc+res; 2 = bf16 relu store;
//      3 = bf16 store w/ cols<qe scaled by LOG2E, cols>=vcol0 -> vT layout;
//      4 = bf16 store scaled by LOG2E.
// ---------------------------------------------------------------------------
template <int TM, int TN, int EPI, int NBUF>
__device__ __forceinline__ void gemm_body(
    int f, int gx, int nwg,
    const unsigned short* __restrict__ A, const unsigned short* __restrict__ Bt,
    void* __restrict__ C, const float* __restrict__ res, int N, int K,
    unsigned short* LDS, unsigned short* vtp = nullptr, int vcol0 = 0, int qe = 0) {
  constexpr bool USE32 = (TM >= 128 && TN >= 128);
  constexpr int WR = (TM >= 128) ? 2 : 1;
  constexpr int WC = 4 / WR;
  constexpr int AM = TM / WR / 16;
  constexpr int AN = TN / WC / 16;
  constexpr int CHA = TM / 8, CHB = TN / 8, CPW = (CHA + CHB) / 4;
  constexpr int BUFSH = (TM + TN) * 64;   // shorts per buffer
  constexpr int DEPTH = NBUF - 1;
  const int tid = threadIdx.x, lane = tid & 63, wv = tid >> 6;
  const int lo = lane & 15, hi = lane >> 4;
  const int l5 = lane >> 5, l31 = lane & 31;
  const int wr = wv / WC, wc = wv % WC;
  const int wg = xcd_swz(f, nwg);
  const int m0 = (wg / gx) * TM, n0 = (wg % gx) * TN;

  f32x4 acc[USE32 ? 1 : AM][USE32 ? 1 : AN];
  f32x16 acc32[USE32 ? 2 : 1][USE32 ? 2 : 1];
  if (USE32) {
#pragma unroll
    for (int i = 0; i < (USE32 ? 2 : 1); ++i)
#pragma unroll
      for (int j = 0; j < (USE32 ? 2 : 1); ++j)
#pragma unroll
        for (int r = 0; r < 16; ++r) acc32[i][j][r] = 0.f;
  } else {
#pragma unroll
    for (int i = 0; i < (USE32 ? 1 : AM); ++i)
#pragma unroll
      for (int j = 0; j < (USE32 ? 1 : AN); ++j) acc[i][j] = f32x4{0.f, 0.f, 0.f, 0.f};
  }

  const int srr  = lane >> 3;                    // row within 8-row chunk
  const int scol = ((lane & 7) ^ srr) * 8;       // pre-swizzled col (halfwords)

  auto stage = [&](int k0, int bsel) {
    unsigned short* Ab = LDS + bsel * BUFSH;
    unsigned short* Bb = Ab + TM * 64;
#pragma unroll
    for (int j = 0; j < CPW; ++j) {
      int c = wv * CPW + j;
      if (c < CHA)
        load_lds16(A + (size_t)(m0 + c * 8 + srr) * K + k0 + scol, Ab + c * 512);
      else {
        int c2 = c - CHA;
        load_lds16(Bt + (size_t)(n0 + c2 * 8 + srr) * K + k0 + scol, Bb + c2 * 512);
      }
    }
  };

  const int nIt = K >> 6;
#pragma unroll
  for (int p = 0; p < DEPTH; ++p)
    if (p < nIt) stage(p << 6, p % NBUF);

  for (int it = 0; it < nIt; ++it) {
    const int bsel = it % NBUF;
    if (NBUF == 1) {
      stage(it << 6, 0);
      asm volatile("s_waitcnt vmcnt(0)" ::: "memory");
    } else if (it + DEPTH < nIt) {
      stage((it + DEPTH) << 6, (it + DEPTH) % NBUF);
      asm volatile("s_waitcnt vmcnt(%0)" :: "n"(DEPTH * CPW) : "memory");
    } else if (it + 1 < nIt) {
      asm volatile("s_waitcnt vmcnt(%0)" :: "n"(CPW) : "memory");
    } else {
      asm volatile("s_waitcnt vmcnt(0)" ::: "memory");
    }
    __builtin_amdgcn_s_barrier();
    __builtin_amdgcn_sched_barrier(0);
    const unsigned short* Ab = LDS + bsel * BUFSH;
    const unsigned short* Bb = Ab + TM * 64;
    if (USE32) {
#pragma unroll
      for (int kk = 0; kk < 4; ++kk) {
        bf16x8 af[2], bfr[2];
#pragma unroll
        for (int i = 0; i < 2; ++i) {
          int row = wr * 64 + i * 32 + l31;
          unsigned by = (unsigned)(row * 128) + ((unsigned)(((kk * 2 + l5) ^ (row & 7))) << 4);
          af[i] = *(const bf16x8*)((const char*)Ab + by);
        }
#pragma unroll
        for (int j = 0; j < 2; ++j) {
          int row = wc * 64 + j * 32 + l31;
          unsigned by = (unsigned)(row * 128) + ((unsigned)(((kk * 2 + l5) ^ (row & 7))) << 4);
          bfr[j] = *(const bf16x8*)((const char*)Bb + by);
        }
        __builtin_amdgcn_s_setprio(1);
#pragma unroll
        for (int i = 0; i < 2; ++i)
#pragma unroll
          for (int j = 0; j < 2; ++j)
            acc32[i][j] = __builtin_amdgcn_mfma_f32_32x32x16_bf16(af[i], bfr[j], acc32[i][j], 0, 0, 0);
        __builtin_amdgcn_s_setprio(0);
      }
    } else {
#pragma unroll
      for (int kk = 0; kk < 2; ++kk) {
        bf16x8 af[AM], bfr[AN];
#pragma unroll
        for (int i = 0; i < AM; ++i) {
          int row = wr * (AM * 16) + i * 16 + lo;
          unsigned by = (unsigned)(row * 128) + ((unsigned)(((kk * 4 + hi) ^ (row & 7))) << 4);
          af[i] = *(const bf16x8*)((const char*)Ab + by);
        }
#pragma unroll
        for (int j = 0; j < AN; ++j) {
          int row = wc * (AN * 16) + j * 16 + lo;
          unsigned by = (unsigned)(row * 128) + ((unsigned)(((kk * 4 + hi) ^ (row & 7))) << 4);
          bfr[j] = *(const bf16x8*)((const char*)Bb + by);
        }
        __builtin_amdgcn_s_setprio(1);
#pragma unroll
        for (int i = 0; i < AM; ++i)
#pragma unroll
          for (int j = 0; j < AN; ++j)
            acc[i][j] = __builtin_amdgcn_mfma_f32_16x16x32_bf16(af[i], bfr[j], acc[i][j], 0, 0, 0);
        __builtin_amdgcn_s_setprio(0);
      }
    }
    __builtin_amdgcn_sched_barrier(0);
    __builtin_amdgcn_s_barrier();
  }

  if (USE32) {
    // C/D 32x32: col = lane&31, row = (r&3) + 8*(r>>2) + 4*(lane>>5)
#pragma unroll
    for (int i = 0; i < 2; ++i)
#pragma unroll
      for (int j = 0; j < 2; ++j) {
        int colb = n0 + wc * 64 + j * 32 + l31;
#pragma unroll
        for (int g = 0; g < 4; ++g) {
          int rowb = m0 + wr * 64 + i * 32 + g * 8 + 4 * l5;
          if (EPI == 3 && colb >= vcol0) {
            int cc = colb - vcol0, hh = cc >> 6, dd = cc & 63;
            int bb = rowb >> 11, tt = rowb & 2047;
            unsigned long long pk = (unsigned long long)f2bf(acc32[i][j][g * 4 + 0])
                                  | ((unsigned long long)f2bf(acc32[i][j][g * 4 + 1]) << 16)
                                  | ((unsigned long long)f2bf(acc32[i][j][g * 4 + 2]) << 32)
                                  | ((unsigned long long)f2bf(acc32[i][j][g * 4 + 3]) << 48);
            *(unsigned long long*)(vtp + ((size_t)((bb * 12 + hh) * 64 + dd)) * 2048 + tt) = pk;
          } else {
#pragma unroll
            for (int rr = 0; rr < 4; ++rr) {
              float v = acc32[i][j][g * 4 + rr];
              size_t idx = (size_t)(rowb + rr) * N + colb;
              if (EPI == 3) {
                if (colb < qe) v *= LOG2E;
                ((unsigned short*)C)[idx] = f2bf(v);
              } else if (EPI == 0) {
                ((unsigned short*)C)[idx] = f2bf(v);
              } else if (EPI == 1) {
                ((float*)C)[idx] = v + res[idx];
              } else if (EPI == 2) {
                ((unsigned short*)C)[idx] = f2bf(fmaxf(v, 0.0f));
              } else {
                ((unsigned short*)C)[idx] = f2bf(v * LOG2E);
              }
            }
          }
        }
      }
  } else {
#pragma unroll
    for (int mi = 0; mi < (USE32 ? 1 : AM); ++mi)
#pragma unroll
      for (int ni = 0; ni < (USE32 ? 1 : AN); ++ni) {
        int row = m0 + wr * (AM * 16) + mi * 16 + hi * 4;
        int col = n0 + wc * (AN * 16) + ni * 16 + lo;
#pragma unroll
        for (int r = 0; r < 4; ++r) {
          float v = acc[mi][ni][r];
          size_t idx = (size_t)(row + r) * N + col;
          if (EPI == 0 || EPI == 3) {
            ((unsigned short*)C)[idx] = f2bf(v);
          } else if (EPI == 1) {
            ((float*)C)[idx] = v + res[idx];
          } else if (EPI == 2) {
            ((unsigned short*)C)[idx] = f2bf(fmaxf(v, 0.0f));
          } else {
            ((unsigned short*)C)[idx] = f2bf(v * LOG2E);
          }
        }
      }
  }
}

template <int TM, int TN, int EPI, int NBUF>
__global__ __launch_bounds__(256)
void gemm_bt(const unsigned short* __restrict__ A, const unsigned short* __restrict__ Bt,
             void* __restrict__ C, const float* __restrict__ res, int N, int K) {
  __shared__ __align__(16) unsigned short LDS[NBUF * (TM + TN) * 64];
  int f = blockIdx.y * gridDim.x + blockIdx.x;
  gemm_body<TM, TN, EPI, NBUF>(f, gridDim.x, gridDim.x * gridDim.y, A, Bt, C, res, N, K, LDS);
}

// ---------------------------------------------------------------------------
// Prep (critical-path only): wq,wk,wv,cwk,cwv transposes + enc conv + rmsnorm1.
// ---------------------------------------------------------------------------
struct PrepArgs {
  const float* wsrc[5];
  unsigned short* wdst[5];
  const float* enc; unsigned short* encb;
  const float* x; const float* snw; unsigned short* normb;
};

__global__ __launch_bounds__(256)
void prep_kernel(PrepArgs a) {
  __shared__ __align__(16) float tile[32][33];
  const int bid = blockIdx.x, tid = threadIdx.x;
  if (bid < 2880) {
    int widx = bid / 576, rem = bid % 576;
    wtrans_tile(a.wsrc[widx], a.wdst[widx], rem, 768, 768, tile, tid);
  } else if (bid < 5952) {
    int i = (bid - 2880) * 256 + tid;
    float4 v = ((const float4*)a.enc)[i];
    unsigned long long pk = (unsigned long long)f2bf(v.x)
                          | ((unsigned long long)f2bf(v.y) << 16)
                          | ((unsigned long long)f2bf(v.z) << 32)
                          | ((unsigned long long)f2bf(v.w) << 48);
    *(unsigned long long*)(a.encb + (size_t)i * 4) = pk;
  } else {
    int row = bid - 5952;
    const float* r = a.x + (size_t)row * 768;
    float x0 = r[tid], x1 = r[tid + 256], x2 = r[tid + 512];
    float s = x0 * x0 + x1 * x1 + x2 * x2;
#pragma unroll
    for (int off = 32; off > 0; off >>= 1) s += __shfl_xor(s, off);
    float* wsm = &tile[0][0];
    int lane = tid & 63, wvv = tid >> 6;
    if (lane == 0) wsm[wvv] = s;
    __syncthreads();
    float tot = wsm[0] + wsm[1] + wsm[2] + wsm[3];
    float rinv = rsqrtf(tot * (1.0f / 768.0f) + 1e-6f);
    unsigned short* o = a.normb + (size_t)row * 768;
    o[tid]       = f2bf(x0 * rinv * a.snw[tid]);
    o[tid + 256] = f2bf(x1 * rinv * a.snw[tid + 256]);
    o[tid + 512] = f2bf(x2 * rinv * a.snw[tid + 512]);
  }
}

// ---------------------------------------------------------------------------
// RMSNorm standalone (stages 2 & 3)
// ---------------------------------------------------------------------------
__global__ __launch_bounds__(256)
void rmsnorm_kernel(const float* __restrict__ in, const float* __restrict__ w,
                    unsigned short* __restrict__ out) {
  int row = blockIdx.x, tid = threadIdx.x;
  const float* r = in + (size_t)row * 768;
  float x0 = r[tid], x1 = r[tid + 256], x2 = r[tid + 512];
  float s = x0 * x0 + x1 * x1 + x2 * x2;
#pragma unroll
  for (int off = 32; off > 0; off >>= 1) s += __shfl_xor(s, off);
  __shared__ float ws_[4];
  int lane = tid & 63, wv = tid >> 6;
  if (lane == 0) ws_[wv] = s;
  __syncthreads();
  float tot = ws_[0] + ws_[1] + ws_[2] + ws_[3];
  float rinv = rsqrtf(tot * (1.0f / 768.0f) + 1e-6f);
  unsigned short* o = out + (size_t)row * 768;
  o[tid]       = f2bf(x0 * rinv * w[tid]);
  o[tid + 256] = f2bf(x1 * rinv * w[tid + 256]);
  o[tid + 512] = f2bf(x2 * rinv * w[tid + 512]);
}

// ---------------------------------------------------------------------------
// Stage-1 mega kernel:
// [0,576) QKV GEMM (Q scaled LOG2E, V->vT1); [576,960) crossKV GEMM (V->vT2);
// [960,5056) pos_bias/out2; [5056,...) deferred prep: wo,cwq,cwo,wi,wo2,rp8.
// ---------------------------------------------------------------------------
struct Stage1Args {
  const unsigned short *normb, *wqkvT, *encb, *wckvT;
  unsigned short *qkv, *ckv, *vT1, *vT2;
  const int* rp; const float* rel;
  float *out1, *out2;
  const float *wo, *cwq, *cwo, *wi, *wo2;
  unsigned short *woT, *wcqT, *wcoT, *wiT, *woT2;
  unsigned char* rp8;
};

__global__ __launch_bounds__(256)
void stage1_kernel(Stage1Args a) {
  __shared__ __align__(16) unsigned short LDS[16384];
  const int bid = blockIdx.x, tid = threadIdx.x;
  if (bid < 576) {
    gemm_body<128, 128, 3, 1>(bid, 18, 576, a.normb, a.wqkvT, a.qkv, nullptr, 2304, 768,
                              LDS, a.vT1, 1536, 768);
  } else if (bid < 960) {
    gemm_body<128, 128, 3, 1>(bid - 576, 12, 384, a.encb, a.wckvT, a.ckv, nullptr, 1536, 768,
                              LDS, a.vT2, 768, 0);
  } else if (bid < 5056) {
    const int p = bid - 960;
    float* rl = (float*)LDS;
    for (int i = tid; i < 384; i += 256) rl[i] = a.rel[i];
    __syncthreads();
    int t = p >> 1;
    int s = (p & 1) * 1024 + tid * 4;
    int4 nb = *(const int4*)(a.rp + (size_t)t * 2048 + s);
#pragma unroll
    for (int h = 0; h < 12; ++h) {
      float4 v = make_float4(rl[nb.x * 12 + h], rl[nb.y * 12 + h],
                             rl[nb.z * 12 + h], rl[nb.w * 12 + h]);
      *(float4*)(a.out1 + ((size_t)h * 2048 + t) * 2048 + s) = v;
    }
    size_t zbase = ((size_t)p * 256 + tid) * 8;
    float4 z = make_float4(0.f, 0.f, 0.f, 0.f);
    *(float4*)(a.out2 + zbase)     = z;
    *(float4*)(a.out2 + zbase + 4) = z;
  } else if (bid < 5632) {
    wtrans_tile(a.wo,  a.woT,  bid - 5056, 768, 768, (float(*)[33])LDS, tid);
  } else if (bid < 6208) {
    wtrans_tile(a.cwq, a.wcqT, bid - 5632, 768, 768, (float(*)[33])LDS, tid);
  } else if (bid < 6784) {
    wtrans_tile(a.cwo, a.wcoT, bid - 6208, 768, 768, (float(*)[33])LDS, tid);
  } else if (bid < 9088) {
    wtrans_tile(a.wi,  a.wiT,  bid - 6784, 768, 3072, (float(*)[33])LDS, tid);
  } else if (bid < 11392) {
    wtrans_tile(a.wo2, a.woT2, bid - 9088, 3072, 768, (float(*)[33])LDS, tid);
  } else {
    int idx = (bid - 11392) * 256 + tid;          // 16 ints -> 16 bytes per thread
    const int4* src = (const int4*)(a.rp + (size_t)idx * 16);
    int4 v0 = src[0], v1 = src[1], v2 = src[2], v3 = src[3];
    uint4 o;
    o.x = (v0.x & 31) | ((v0.y & 31) << 8) | ((v0.z & 31) << 16) | ((v0.w & 31) << 24);
    o.y = (v1.x & 31) | ((v1.y & 31) << 8) | ((v1.z & 31) << 16) | ((v1.w & 31) << 24);
    o.z = (v2.x & 31) | ((v2.y & 31) << 8) | ((v2.z & 31) << 16) | ((v2.w & 31) << 24);
    o.w = (v3.x & 31) | ((v3.y & 31) << 8) | ((v3.z & 31) << 16) | ((v3.w & 31) << 24);
    ((uint4*)a.rp8)[idx] = o;
  }
}

// ---------------------------------------------------------------------------
// Single-q attention tile compute (swapped operands; lane owns q = lane&15).
// FIXED-BASE softmax: p = exp2(s), no max subtraction.
// ---------------------------------------------------------------------------
template <bool SELF>
__device__ __forceinline__ void attn_qcomp(
    const bf16x8& qf0, const bf16x8& qf1, f32x4* Oc, float& l_,
    const unsigned* nb4, const float* rel_l, int qrow, bool edge, int s0,
    const unsigned short* Kb, const unsigned short* Vb, int lo, int hi) {
  f32x4 S[4];
  __builtin_amdgcn_s_setprio(1);
#pragma unroll
  for (int ct = 0; ct < 4; ++ct) {
    int krow = ct * 16 + lo;
    unsigned by0 = ((unsigned)(krow * 128 + hi * 16))      ^ ((unsigned)(krow & 7) << 4);
    unsigned by1 = ((unsigned)(krow * 128 + 64 + hi * 16)) ^ ((unsigned)(krow & 7) << 4);
    bf16x8 kf0 = *(const bf16x8*)((const char*)Kb + by0);
    bf16x8 kf1 = *(const bf16x8*)((const char*)Kb + by1);
    f32x4 sa = f32x4{0.f, 0.f, 0.f, 0.f};
    sa = __builtin_amdgcn_mfma_f32_16x16x32_bf16(kf0, qf0, sa, 0, 0, 0);
    sa = __builtin_amdgcn_mfma_f32_16x16x32_bf16(kf1, qf1, sa, 0, 0, 0);
    S[ct] = sa;
  }
  __builtin_amdgcn_s_setprio(0);

  if constexpr (SELF) {
#pragma unroll
    for (int ct = 0; ct < 4; ++ct) {
#pragma unroll
      for (int r = 0; r < 4; ++r) {
        int s = s0 + ct * 16 + hi * 4 + r;
        float sc = S[ct][r] + rel_l[(nb4[ct] >> (8 * r)) & 31u];
        if (edge && s > qrow) sc = -1e30f;
        S[ct][r] = sc;
      }
    }
  }

  float rs = 0.f;
#pragma unroll
  for (int ct = 0; ct < 4; ++ct)
#pragma unroll
    for (int r = 0; r < 4; ++r) { float e = fexp2(S[ct][r]); S[ct][r] = e; rs += e; }
  l_ += rs;

  short4v pf[4];
#pragma unroll
  for (int ct = 0; ct < 4; ++ct) {
    union { unsigned u[2]; short4v s; } cv;
    cv.u[0] = cvt_pk_bf16(S[ct][0], S[ct][1]);
    cv.u[1] = cvt_pk_bf16(S[ct][2], S[ct][3]);
    pf[ct] = cv.s;
  }

  __builtin_amdgcn_s_setprio(1);
#pragma unroll
  for (int dt = 0; dt < 4; ++dt) {
    int vrow = dt * 16 + lo;
#pragma unroll
    for (int ct = 0; ct < 4; ++ct) {
      unsigned vb = ((unsigned)(vrow * 128 + ct * 32 + hi * 8)) ^ ((unsigned)(vrow & 7) << 4);
      short4v vf = *(const short4v*)((const char*)Vb + vb);
      Oc[dt] = mfma16(vf, pf[ct], Oc[dt]);
    }
  }
  __builtin_amdgcn_s_setprio(0);
}

__device__ __forceinline__ void attn_store(f32x4* Oc, float l_, unsigned short* yr) {
  l_ += __shfl_xor(l_, 16);
  l_ += __shfl_xor(l_, 32);
  float inv = 1.0f / l_;
#pragma unroll
  for (int dt = 0; dt < 4; ++dt) {
    unsigned long long pk = (unsigned long long)f2bf(Oc[dt][0] * inv)
                          | ((unsigned long long)f2bf(Oc[dt][1] * inv) << 16)
                          | ((unsigned long long)f2bf(Oc[dt][2] * inv) << 32)
                          | ((unsigned long long)f2bf(Oc[dt][3] * inv) << 48);
    *(unsigned long long*)(yr + dt * 16) = pk;
  }
}

// ---------------------------------------------------------------------------
// Self-attention: PAIRED q-tiles (i, 31-i), 8 WAVES (512 thr): waves 0-3 own
// q-set A, waves 4-7 own q-set B. K/V staged once per block (each wave loads
// one K-chunk + one V-chunk). Bias dwords direct from global rp8 (L2).
// grid (16,12,2). LDS 32KB -> 2 blocks/CU = 16 waves/CU.
// ---------------------------------------------------------------------------
__global__ __launch_bounds__(512)
void attn_self_kernel(const unsigned short* __restrict__ qp,   // qkv, stride 2304
                      const unsigned short* __restrict__ kp,   // qkv+768
                      const unsigned short* __restrict__ vT,
                      const unsigned char* __restrict__ rp8,
                      const float* __restrict__ rel_emb,
                      unsigned short* __restrict__ yp) {
  __shared__ __align__(16) unsigned short Kls[2][4096];
  __shared__ __align__(16) unsigned short Vls[2][4096];
  __shared__ float rel_l[32];

  const int tid = threadIdx.x, lane = tid & 63, wv = tid >> 6;
  const int lo = lane & 15, hi = lane >> 4;
  const int qset = wv >> 2, wq = wv & 3;
  const int wg = xcd_swz(blockIdx.x + 16 * (blockIdx.y + 12 * blockIdx.z), 384);
  const int xq = wg & 15, h = (wg >> 4) % 12, b = (wg >> 4) / 12;
  const int qta = xq, qtb = 31 - xq;
  const int ntiles = qtb + 1;
  const int qt = qset ? qtb : qta;

  if (tid < 32) rel_l[tid] = rel_emb[tid * 12 + h] * LOG2E;

  const int q = qt * 64 + wq * 16 + lo;
  const unsigned short* qr = qp + (size_t)(b * T5_T + q) * 2304 + h * 64 + hi * 8;
  const bf16x8 qf0 = *(const bf16x8*)qr;
  const bf16x8 qf1 = *(const bf16x8*)(qr + 32);
  const unsigned char* rpq = rp8 + (size_t)q * 2048 + hi * 4;

  f32x4 Oc[4];
  float l_ = 0.f;
#pragma unroll
  for (int i = 0; i < 4; ++i) Oc[i] = f32x4{0.f, 0.f, 0.f, 0.f};

  const int krr = lane >> 3;
  const int kd0 = ((lane & 7) ^ krr) * 8;

  auto stage = [&](int kt, int bsel) {
    const int s0 = kt * 64;
    int rr = wv * 8 + krr;     // 8 waves x 8 rows = 64 rows
    load_lds16(kp + (size_t)(b * 2048 + s0 + rr) * 2304 + h * 64 + kd0, &Kls[bsel][wv * 512]);
    load_lds16(vT + (size_t)((b * 12 + h) * 64 + rr) * 2048 + s0 + kd0,  &Vls[bsel][wv * 512]);
  };

  stage(0, 0);

  for (int kt = 0; kt < ntiles; ++kt) {
    const int bsel = kt & 1;
    const int s0 = kt * 64;
    asm volatile("s_waitcnt vmcnt(0)" ::: "memory");
    __syncthreads();
    const bool active = qset || (kt <= qta);
    unsigned nb4[4];
    if (active) {
#pragma unroll
      for (int ct = 0; ct < 4; ++ct) nb4[ct] = *(const unsigned*)(rpq + s0 + ct * 16);
    }
    if (kt + 1 < ntiles) stage(kt + 1, bsel ^ 1);

    if (active)
      attn_qcomp<true>(qf0, qf1, Oc, l_, nb4, rel_l, q, kt == qt, s0,
                       &Kls[bsel][0], &Vls[bsel][0], lo, hi);
  }

#if !__has_builtin(__builtin_amdgcn_mfma_f32_16x16x16bf16_1k)
  asm volatile("s_nop 7\n\ts_nop 7" ::: );
#endif

  attn_store(Oc, l_, yp + (size_t)(b * T5_T + q) * 768 + h * 64 + hi * 4);
}

// ---------------------------------------------------------------------------
// Cross-attention: PAIRED q-tiles (2i, 2i+1), 8 waves (512 thr): waves 0-3 own
// q-set A, waves 4-7 own q-set B. grid (16,12,2). LDS 32KB.
// ---------------------------------------------------------------------------
__global__ __launch_bounds__(512)
void attn_cross_kernel(const unsigned short* __restrict__ qp,   // cq, stride 768
                       const unsigned short* __restrict__ kp,   // ckv, stride 1536
                       const unsigned short* __restrict__ vT,
                       unsigned short* __restrict__ yp) {
  __shared__ __align__(16) unsigned short Kls[2][4096];
  __shared__ __align__(16) unsigned short Vls[2][4096];

  const int tid = threadIdx.x, lane = tid & 63, wv = tid >> 6;
  const int lo = lane & 15, hi = lane >> 4;
  const int qset = wv >> 2, wq = wv & 3;
  const int wg = xcd_swz(blockIdx.x + 16 * (blockIdx.y + 12 * blockIdx.z), 384);
  const int xq = wg & 15, h = (wg >> 4) % 12, b = (wg >> 4) / 12;

  const int q = (xq * 2 + qset) * 64 + wq * 16 + lo;
  const unsigned short* qr = qp + (size_t)(b * T5_T + q) * 768 + h * 64 + hi * 8;
  const bf16x8 qf0 = *(const bf16x8*)qr;
  const bf16x8 qf1 = *(const bf16x8*)(qr + 32);

  f32x4 Oc[4];
  float l_ = 0.f;
#pragma unroll
  for (int i = 0; i < 4; ++i) Oc[i] = f32x4{0.f, 0.f, 0.f, 0.f};

  const int krr = lane >> 3;
  const int kd0 = ((lane & 7) ^ krr) * 8;

  auto stage = [&](int kt, int bsel) {
    const int s0 = kt * 64;
    int rr = wv * 8 + krr;
    load_lds16(kp + (size_t)(b * 2048 + s0 + rr) * 1536 + h * 64 + kd0, &Kls[bsel][wv * 512]);
    load_lds16(vT + (size_t)((b * 12 + h) * 64 + rr) * 2048 + s0 + kd0, &Vls[bsel][wv * 512]);
  };

  stage(0, 0);

  for (int kt = 0; kt < 32; ++kt) {
    const int bsel = kt & 1;
    asm volatile("s_waitcnt vmcnt(0)" ::: "memory");
    __syncthreads();
    if (kt + 1 < 32) stage(kt + 1, bsel ^ 1);
    attn_qcomp<false>(qf0, qf1, Oc, l_, nullptr, nullptr, 0, false, kt * 64,
                      &Kls[bsel][0], &Vls[bsel][0], lo, hi);
  }

#if !__has_builtin(__builtin_amdgcn_mfma_f32_16x16x16bf16_1k)
  asm volatile("s_nop 7\n\ts_nop 7" ::: );
#endif

  attn_store(Oc, l_, yp + (size_t)(b * T5_T + q) * 768 + h * 64 + hi * 4);
}

// ---------------------------------------------------------------------------
extern "C" void kernel_launch(void* const* d_in, const int* in_sizes, int n_in,
                              void* d_out, int out_size, void* d_ws, size_t ws_size,
                              hipStream_t stream) {
  (void)in_sizes; (void)n_in; (void)out_size; (void)ws_size;
  const float* x    = (const float*)d_in[0];
  const int*   rp   = (const int*)d_in[2];
  const float* enc  = (const float*)d_in[3];
  const float* sn_w = (const float*)d_in[5];
  const float* wq   = (const float*)d_in[6];
  const float* wk   = (const float*)d_in[7];
  const float* wvw  = (const float*)d_in[8];
  const float* wo   = (const float*)d_in[9];
  const float* rel  = (const float*)d_in[10];
  const float* cn_w = (const float*)d_in[11];
  const float* cwq  = (const float*)d_in[12];
  const float* cwk  = (const float*)d_in[13];
  const float* cwv  = (const float*)d_in[14];
  const float* cwo  = (const float*)d_in[15];
  const float* pn_w = (const float*)d_in[16];
  const float* wi   = (const float*)d_in[17];
  const float* wo2  = (const float*)d_in[18];

  float* out0 = (float*)d_out;
  float* out1 = out0 + (size_t)NROW * T5_D;
  float* out2 = out1 + (size_t)T5_H * T5_T * T5_T;

  char* ws = (char*)d_ws;
  size_t off = 0;
  auto alloc = [&](size_t bytes) { char* p = ws + off; off += (bytes + 255) & ~(size_t)255; return p; };
  unsigned short* wqkvT = (unsigned short*)alloc((size_t)2304 * 768 * 2);
  unsigned short* woT   = (unsigned short*)alloc((size_t)768 * 768 * 2);
  unsigned short* wckvT = (unsigned short*)alloc((size_t)1536 * 768 * 2);
  unsigned short* wcqT  = (unsigned short*)alloc((size_t)768 * 768 * 2);
  unsigned short* wcoT  = (unsigned short*)alloc((size_t)768 * 768 * 2);
  unsigned short* wiT   = (unsigned short*)alloc((size_t)3072 * 768 * 2);
  unsigned short* woT2  = (unsigned short*)alloc((size_t)768 * 3072 * 2);
  unsigned short* normb = (unsigned short*)alloc((size_t)NROW * 768 * 2);
  unsigned short* encb  = (unsigned short*)alloc((size_t)NROW * 768 * 2);
  unsigned short* ybuf  = (unsigned short*)alloc((size_t)NROW * 768 * 2);
  unsigned short* cq    = (unsigned short*)alloc((size_t)NROW * 768 * 2);
  float*          attn  = (float*)alloc((size_t)NROW * 768 * 4);
  unsigned char*  rp8p  = (unsigned char*)alloc((size_t)2048 * 2048);
  unsigned short* qkv   = (unsigned short*)alloc((size_t)NROW * 2304 * 2);
  unsigned short* ckv   = (unsigned short*)alloc((size_t)NROW * 1536 * 2);
  unsigned short* vT1   = (unsigned short*)alloc((size_t)24 * 64 * 2048 * 2);
  unsigned short* vT2   = (unsigned short*)alloc((size_t)24 * 64 * 2048 * 2);
  unsigned short* ffh   = (unsigned short*)alloc((size_t)NROW * 3072 * 2);

  dim3 blk(256);

  // prep (critical-path only): wq/wk/wv/cwk/cwv + enc conv + rmsnorm1
  {
    PrepArgs pa;
    pa.wsrc[0] = wq;  pa.wdst[0] = wqkvT;
    pa.wsrc[1] = wk;  pa.wdst[1] = wqkvT + 768 * 768;
    pa.wsrc[2] = wvw; pa.wdst[2] = wqkvT + 2 * 768 * 768;
    pa.wsrc[3] = cwk; pa.wdst[3] = wckvT;
    pa.wsrc[4] = cwv; pa.wdst[4] = wckvT + 768 * 768;
    pa.enc = enc; pa.encb = encb;
    pa.x = x; pa.snw = sn_w; pa.normb = normb;
    prep_kernel<<<10048, blk, 0, stream>>>(pa);
  }

  // stage1 mega: QKV+crossKV GEMMs + pos_bias/out2 + deferred weight prep
  {
    Stage1Args sa;
    sa.normb = normb; sa.wqkvT = wqkvT; sa.encb = encb; sa.wckvT = wckvT;
    sa.qkv = qkv; sa.ckv = ckv; sa.vT1 = vT1; sa.vT2 = vT2;
    sa.rp = rp; sa.rel = rel; sa.out1 = out1; sa.out2 = out2;
    sa.wo = wo; sa.cwq = cwq; sa.cwo = cwo; sa.wi = wi; sa.wo2 = wo2;
    sa.woT = woT; sa.wcqT = wcqT; sa.wcoT = wcoT; sa.wiT = wiT; sa.woT2 = woT2;
    sa.rp8 = rp8p;
    stage1_kernel<<<12416, blk, 0, stream>>>(sa);
  }

  // self-attention (paired q-tiles, 8-wave blocks, exp2 softmax)
  attn_self_kernel<<<dim3(16, 12, 2), dim3(512), 0, stream>>>(qkv, qkv + 768, vT1, rp8p, rel, ybuf);
  // O-proj + residual -> attn (f32)
  gemm_bt<64, 64, 1, 3><<<dim3(12, 64), blk, 0, stream>>>(ybuf, woT, attn, x, 768, 768);

  // cross-attention
  rmsnorm_kernel<<<NROW, blk, 0, stream>>>(attn, cn_w, normb);
  gemm_bt<64, 64, 4, 3><<<dim3(12, 64), blk, 0, stream>>>(normb, wcqT, cq, nullptr, 768, 768);
  attn_cross_kernel<<<dim3(16, 12, 2), dim3(512), 0, stream>>>(cq, ckv, vT2, ybuf);
  gemm_bt<64, 64, 1, 3><<<dim3(12, 64), blk, 0, stream>>>(ybuf, wcoT, attn, attn, 768, 768);

  // FFN
  rmsnorm_kernel<<<NROW, blk, 0, stream>>>(attn, pn_w, normb);
  gemm_bt<128, 128, 2, 1><<<dim3(24, 32), blk, 0, stream>>>(normb, wiT, ffh, nullptr, 3072, 768);
  gemm_bt<64, 64, 1, 3><<<dim3(12, 64), blk, 0, stream>>>(ffh, woT2, out0, attn, 768, 3072);
}